// Round 5
// baseline (729.333 us; speedup 1.0000x reference)
//
#include <hip/hip_runtime.h>
#include <hip/hip_fp16.h>

// GCN 3-layer, N=500000, E=8000000 — two-level binned CSR + register-pull.
//
// Algebra (aggregation commutes with linear maps):
//   L1: (A_hat @ inp) @ W1          -> 3-float walk of fp16 u0h (fused into build2)
//   L2: [A_hat h1, A_hat inp] @ W2  -> 29-float pull of fp16 h1s rows (fused W2/W3)
//   L3: A_hat (h' @ W3)             -> 1-half pull of fp16 zs (1MB, L2-resident)
// A_hat v = dinv * (sum_nbr(dinv*v) + dinv*v_self)  (pre/post scale).
//
// LESSON (R8, R10 prev session): per-edge LDS float atomics lose to register pulls.
// LESSON (R1): persistent-grid pull2 blew VGPR (occ 11%); src-chunk-sort gave
// zero FETCH reduction (no coherent window at deg~16).
// LESSON (R2): deeper MLP null -> pull2 is REQUEST-RATE-bound on random 64B
// gathers (~3.4TB/s fabric ceiling); byte-minimal. FROZEN at R0 form (~152us).
// LESSON (R2): NT hints belong on STREAMS, not on reuse paths (NT list loads
// cost +30MB FETCH in pull2).
// LESSON (R4): __builtin_nontemporal_* rejects HIP_vector_type (float4/uint4);
// cast through ext_vector_type (v4f/v4u) instead.
// THIS ROUND (= R3 design, compile-fixed): (1) delete build1 — deg via
// fire-and-forget global atomics in split + tiny prep kernel for u0/u0h;
// hist/scan/rowdeg folded into build2. (2) NT-stream discipline in build2 so
// the 4MB u0h gather table stays L2-resident.
//
// Passes: split (512thr/8192-edge blocks: in-LDS counting sort -> full-line
//      flush; + deg[dst] global atomics)
//   -> prep (1 thr/node: deg -> di -> u0/u0h; pure 20MB stream)
//   -> build2 (1 WG/bucket: LDS hist -> wave-scan -> rowdeg; in-LDS node-sort
//      (full bucket in dest[68KB]) -> NT flush; then 2-lane/node register walk
//      x2 rounds gathers u0h (L2-resident) + W1/relu -> fp16 h1s)
//   -> pull2 (4 lanes/node register pull of 64B h1s rows, fused W2/relu/W3)
//   -> pull3 (1 thread/node pull of fp16 zs + final scale)

#define CAPB       17920     // per-bucket capacity: mean 16384, sigma 128 (+12 sigma)
#define BSH2       10        // 1024-node coarse buckets
#define BN2        1024
#define PACK_SHIFT 19        // src < 2^19 = 524288 > N
#define PACK_MASK  0x7FFFFu
#define SPLIT_CH   8192      // edges per split block (16/thread, 512 threads)
#define DEST_CAP   17408     // full-bucket LDS staging: mean+8sigma (68KB)

typedef int v4i __attribute__((ext_vector_type(4)));
typedef float v4f __attribute__((ext_vector_type(4)));
typedef unsigned int v4u __attribute__((ext_vector_type(4)));

__global__ __launch_bounds__(512) void split_kernel(
    const int* __restrict__ src, const int* __restrict__ dst,
    unsigned int* __restrict__ gcur, unsigned int* __restrict__ deg,
    unsigned int* __restrict__ ebuf, int E) {
    __shared__ unsigned int hist[512];      // counts -> running cursors
    __shared__ unsigned int delta[512];     // gbase - local_excl_base
    __shared__ unsigned int wsum[8];        // per-wave scan partials
    __shared__ unsigned int tots;
    __shared__ unsigned int staged[SPLIT_CH];     // 32KB
    __shared__ unsigned short bid[SPLIT_CH];      // 16KB
    int tid = threadIdx.x;
    long long base = (long long)blockIdx.x * SPLIT_CH;
    hist[tid] = 0;
    __syncthreads();
    unsigned int s[16], d[16];
    if (base + SPLIT_CH <= E) {          // full chunk: int4 nontemporal loads
        const v4i* s4 = (const v4i*)(src + base);
        const v4i* d4 = (const v4i*)(dst + base);
#pragma unroll
        for (int i = 0; i < 4; i++) {
            v4i sv = __builtin_nontemporal_load(s4 + tid + 512 * i);
            v4i dv = __builtin_nontemporal_load(d4 + tid + 512 * i);
            s[4 * i + 0] = (unsigned int)sv.x; d[4 * i + 0] = (unsigned int)dv.x;
            s[4 * i + 1] = (unsigned int)sv.y; d[4 * i + 1] = (unsigned int)dv.y;
            s[4 * i + 2] = (unsigned int)sv.z; d[4 * i + 2] = (unsigned int)dv.z;
            s[4 * i + 3] = (unsigned int)sv.w; d[4 * i + 3] = (unsigned int)dv.w;
        }
#pragma unroll
        for (int i = 0; i < 16; i++) atomicAdd(&hist[d[i] >> BSH2], 1u);
        // fire-and-forget per-node degree counts (no return -> no wait)
#pragma unroll
        for (int i = 0; i < 16; i++) atomicAdd(&deg[d[i]], 1u);
    } else {                              // tail chunk: scalar with bounds
#pragma unroll
        for (int i = 0; i < 16; i++) {
            long long e = base + tid + 512 * i;
            bool ok = e < E;
            s[i] = ok ? (unsigned int)src[e] : 0u;
            d[i] = ok ? (unsigned int)dst[e] : 0xFFFFFFFFu;
            if (ok) { atomicAdd(&hist[d[i] >> BSH2], 1u); atomicAdd(&deg[d[i]], 1u); }
        }
    }
    __syncthreads();
    unsigned int c = hist[tid];
    // wave-shuffle inclusive scan (6 steps), then serial scan of 8 wave sums
    unsigned int v = c;
#pragma unroll
    for (int off = 1; off < 64; off <<= 1) {
        unsigned int t = __shfl_up(v, off, 64);
        if ((tid & 63) >= off) v += t;
    }
    int wv = tid >> 6;
    if ((tid & 63) == 63) wsum[wv] = v;
    __syncthreads();
    if (tid == 0) {
        unsigned int r = 0;
#pragma unroll
        for (int i = 0; i < 8; i++) { unsigned int t = wsum[i]; wsum[i] = r; r += t; }
        tots = r;
    }
    __syncthreads();
    unsigned int excl = v + wsum[wv] - c;      // exclusive prefix
    unsigned int gb = c ? atomicAdd(&gcur[tid], c) : 0u;
    delta[tid] = gb - excl;
    hist[tid] = excl;                     // running cursor
    __syncthreads();
#pragma unroll
    for (int i = 0; i < 16; i++) {
        if (d[i] != 0xFFFFFFFFu) {
            unsigned int bb = d[i] >> BSH2;
            unsigned int pos = atomicAdd(&hist[bb], 1u);
            staged[pos] = s[i] | ((d[i] & (BN2 - 1)) << PACK_SHIFT);
            bid[pos] = (unsigned short)bb;
        }
    }
    __syncthreads();
    unsigned int tot = tots;
    for (unsigned int i = tid; i < tot; i += 512) {   // mostly-consecutive full lines
        unsigned int bb = bid[i];
        unsigned int rel = delta[bb] + i;             // position within bucket
        if (rel < CAPB)
            __builtin_nontemporal_store(staged[i], &ebuf[(size_t)bb * CAPB + rel]);
    }
}

// prep: 1 thread/node pure stream — deg -> di -> u0 {inp*di, di} fp32 and
// u0h {x0*di, x1*di, y1*di, 0} fp16 (4MB gather table for build2's walk).
__global__ __launch_bounds__(256) void prep_kernel(
    const unsigned int* __restrict__ deg, const float* __restrict__ x,
    const float* __restrict__ y1, float4* __restrict__ u0,
    uint2* __restrict__ u0h, int N) {
    int n = blockIdx.x * 256 + threadIdx.x;
    if (n >= N) return;
    unsigned int cnt = deg[n];
    float di = rsqrtf((float)cnt + 1.0f);
    float2 xv = ((const float2*)x)[n];
    float v0 = xv.x * di, v1 = xv.y * di, v2 = y1[n] * di;
    u0[n] = make_float4(v0, v1, v2, di);
    union { __half2 h2[2]; uint2 u; } pk;
    pk.h2[0] = __floats2half2_rn(v0, v1);
    pk.h2[1] = __floats2half2_rn(v2, 0.f);
    u0h[n] = pk.u;
}

// Fetch one sorted list entry: LDS dest if staged, else already-written seg2.
__device__ __forceinline__ unsigned int sfetch2(const unsigned int* dest,
                                                const unsigned int* seg2,
                                                unsigned int j) {
    return (j < DEST_CAP) ? dest[j] : seg2[j];
}

// Walk one node with 2 paired lanes (q = tid&1, pair tid^1): gather u0h[src]
// over [o,e), reduce via shfl, run W1/relu epilogue, store 64B fp16 row (NT).
// u0h loads are PLAIN (the one access we want L2 to retain).
__device__ __forceinline__ void walk_node(
    int gn, int q, unsigned int o, unsigned int e,
    const unsigned int* __restrict__ dest, const unsigned int* __restrict__ seg2,
    const uint2* __restrict__ u0h, const float4* __restrict__ u0,
    const float* __restrict__ W1, const float* __restrict__ b1,
    uint4* __restrict__ h1s) {
    unsigned int cnt = e - o;
    unsigned int hcnt = cnt >> 1;
    unsigned int j0 = o + (q ? hcnt : 0), j1 = q ? e : o + hcnt;
    v4f u = __builtin_nontemporal_load((const v4f*)&u0[gn]);
    float sx = q ? 0.f : u.x, sy = q ? 0.f : u.y, sz = q ? 0.f : u.z;
    unsigned int j = j0;
    for (; j + 4 <= j1; j += 4) {
        unsigned int i0 = sfetch2(dest, seg2, j);
        unsigned int i1 = sfetch2(dest, seg2, j + 1);
        unsigned int i2 = sfetch2(dest, seg2, j + 2);
        unsigned int i3 = sfetch2(dest, seg2, j + 3);
        union { uint2 u; __half2 h[2]; } g0, g1, g2, g3;
        g0.u = u0h[i0]; g1.u = u0h[i1]; g2.u = u0h[i2]; g3.u = u0h[i3];
        float2 a0 = __half22float2(g0.h[0]), c0 = __half22float2(g0.h[1]);
        float2 a1 = __half22float2(g1.h[0]), c1 = __half22float2(g1.h[1]);
        float2 a2 = __half22float2(g2.h[0]), c2 = __half22float2(g2.h[1]);
        float2 a3 = __half22float2(g3.h[0]), c3 = __half22float2(g3.h[1]);
        sx += (a0.x + a1.x) + (a2.x + a3.x);
        sy += (a0.y + a1.y) + (a2.y + a3.y);
        sz += (c0.x + c1.x) + (c2.x + c3.x);
    }
    for (; j < j1; j++) {
        union { uint2 u; __half2 h[2]; } g;
        g.u = u0h[sfetch2(dest, seg2, j)];
        float2 a = __half22float2(g.h[0]);
        sx += a.x; sy += a.y; sz += __half2float(g.h[1].x);
    }
    sx += __shfl_xor(sx, 1, 64);      // pair tid^1 = same node
    sy += __shfl_xor(sy, 1, 64);
    sz += __shfl_xor(sz, 1, 64);
    float di = u.w;
    float a0 = sx * di, a1 = sy * di, a2 = sz * di;
    float hv[16];
#pragma unroll
    for (int i = 0; i < 16; i++) {
        int k = 16 * q + i;
        if (k < 29) {
            float vv = fmaf(a0, W1[k], fmaf(a1, W1[29 + k], fmaf(a2, W1[58 + k], b1[k])));
            hv[i] = fmaxf(vv, 0.0f) * di;   // pre-scaled for next aggregation
        } else {
            hv[i] = (k == 29) ? a0 : (k == 30) ? a1 : a2;   // stash A_hat·inp
        }
    }
    union { __half2 h2[8]; v4u u4[2]; } pk;
#pragma unroll
    for (int i = 0; i < 8; i++) pk.h2[i] = __floats2half2_rn(hv[2 * i], hv[2 * i + 1]);
    v4u* row = (v4u*)(h1s + (size_t)gn * 4 + 2 * q);
    __builtin_nontemporal_store(pk.u4[0], row);
    __builtin_nontemporal_store(pk.u4[1], row + 1);
}

// build2 v3: absorbs build1 — LDS hist (cur reused) -> wave-scan -> rowdeg;
// single-pass in-LDS node-sort (full bucket in dest[68KB]) -> NT flush ->
// 2 walk rounds (2 lanes/node x 512 nodes each) gathering u0h + W1/relu -> h1s.
// NT-stream discipline: seg loads, seg2/h1s/rowdeg stores, u0 loads all NT;
// u0h gathers plain so the 4MB table owns the XCD L2.
// LDS: cur 4KB + base2 4KB + dest 68KB = 76KB -> 2 WG/CU.
__global__ __launch_bounds__(1024) void build2_kernel(
    const unsigned int* __restrict__ gcur, const unsigned int* __restrict__ ebuf,
    const float4* __restrict__ u0, const uint2* __restrict__ u0h,
    const float* __restrict__ W1, const float* __restrict__ b1,
    unsigned int* __restrict__ rowdeg,
    unsigned int* __restrict__ ebuf2, uint4* __restrict__ h1s, int N) {
    __shared__ unsigned int cur[BN2];        // 4KB hist -> running cursors
    __shared__ unsigned int base2[BN2 + 1];  // 4KB per-node offsets for the walk
    __shared__ unsigned int wsum[16];
    __shared__ unsigned int dest[DEST_CAP];  // 68KB full-bucket staging
    int b = blockIdx.x, tid = threadIdx.x;
    int gn0 = (b << BSH2);
    int n = gn0 + tid;
    unsigned int T = gcur[b]; if (T > CAPB) T = CAPB;
    const unsigned int* seg = ebuf + (size_t)b * CAPB;
    unsigned int* seg2 = ebuf2 + (size_t)b * CAPB;
    cur[tid] = 0;
    __syncthreads();
    // pass 1: histogram (NT read — stream, no L2 allocate)
    for (unsigned int f = tid; f < T; f += 1024)
        atomicAdd(&cur[__builtin_nontemporal_load(seg + f) >> PACK_SHIFT], 1u);
    __syncthreads();
    unsigned int cnt = cur[tid];
    unsigned int v = cnt;
#pragma unroll
    for (int off = 1; off < 64; off <<= 1) {
        unsigned int t = __shfl_up(v, off, 64);
        if ((tid & 63) >= off) v += t;
    }
    int wv = tid >> 6;
    if ((tid & 63) == 63) wsum[wv] = v;
    __syncthreads();
    if (tid == 0) {
        unsigned int r = 0;
#pragma unroll
        for (int i = 0; i < 16; i++) { unsigned int t = wsum[i]; wsum[i] = r; r += t; }
    }
    __syncthreads();
    unsigned int base = v + wsum[wv] - cnt;      // exclusive
    if (n < N) __builtin_nontemporal_store(base | (cnt << 16), &rowdeg[n]);
    cur[tid] = base; base2[tid] = base;
    if (tid == 0) base2[BN2] = T;
    __syncthreads();
    // pass 2: scatter records node-sorted into dest (overflow -> seg2 direct)
    for (unsigned int f = tid; f < T; f += 1024) {
        unsigned int p = __builtin_nontemporal_load(seg + f);
        unsigned int dloc = p >> PACK_SHIFT;
        unsigned int pos = atomicAdd(&cur[dloc], 1u);
        unsigned int s = p & PACK_MASK;
        if (pos < DEST_CAP) dest[pos] = s;
        else                seg2[pos] = s;       // essentially never (T<=mean+8s)
    }
    __syncthreads();
    // sequential full-line NT flush (dest read-only from here)
    unsigned int m = T < DEST_CAP ? T : DEST_CAP;
    for (unsigned int i = tid; i < m; i += 1024)
        __builtin_nontemporal_store(dest[i], &seg2[i]);
    // fused layer-1 walk: 2 threads/node, 2 rounds of 512 nodes
    int q = tid & 1;
    int l0 = tid >> 1;
    int gnA = gn0 + l0;
    if (gnA < N)
        walk_node(gnA, q, base2[l0], base2[l0 + 1], dest, seg2, u0h, u0, W1, b1, h1s);
    int l1 = l0 + 512;
    int gnB = gn0 + l1;
    if (gnB < N)
        walk_node(gnB, q, base2[l1], base2[l1 + 1], dest, seg2, u0h, u0, W1, b1, h1s);
}

__device__ __forceinline__ void unpack8(float4 r, float* o) {
    union { float4 f; __half2 h[4]; } u; u.f = r;
    float2 a = __half22float2(u.h[0]); o[0] = a.x; o[1] = a.y;
    float2 b = __half22float2(u.h[1]); o[2] = b.x; o[3] = b.y;
    float2 c = __half22float2(u.h[2]); o[4] = c.x; o[5] = c.y;
    float2 d = __half22float2(u.h[3]); o[6] = d.x; o[7] = d.y;
}

// Fused layer-2 pull + W2/relu/W3: 4 lanes/node, 64B row gather/edge,
// unroll-4 register accumulation, LDS W2, shfl_xor reduce. Writes fp16 zs + out.
// FROZEN at R0 form: request-rate-bound on random 64B gathers (R2: deeper MLP
// null; R1: locality sort null). VGPR 40, occupancy ~61%.
__global__ __launch_bounds__(256) void pull2_kernel(
    const float4* __restrict__ h1f4, const unsigned int* __restrict__ rowdeg,
    const unsigned int* __restrict__ ebuf2, const float4* __restrict__ u0,
    const float* __restrict__ x, const float* __restrict__ y1,
    const float* __restrict__ W2, const float* __restrict__ b2,
    const float* __restrict__ W3, const float* __restrict__ b3,
    __half* __restrict__ zs, float* __restrict__ out, int N) {
    __shared__ float W2l[32 * 29];
    for (int i = threadIdx.x; i < 32 * 29; i += 256) W2l[i] = W2[i];
    int t = blockIdx.x * 256 + threadIdx.x;
    int n = t >> 2, q = t & 3;
    __syncthreads();
    if (n >= N) return;
    unsigned int rd = rowdeg[n];
    const unsigned int* lst = ebuf2 + (size_t)(n >> BSH2) * CAPB + (rd & 0xFFFFu);
    unsigned int cnt = rd >> 16;
    float acc[8] = {0.f, 0.f, 0.f, 0.f, 0.f, 0.f, 0.f, 0.f};
    unsigned int j = 0;
    for (; j + 4 <= cnt; j += 4) {        // 4 outstanding 64B row fetches
        unsigned int s0 = lst[j], s1 = lst[j + 1], s2 = lst[j + 2], s3 = lst[j + 3];
        float4 r0 = h1f4[(size_t)s0 * 4 + q];
        float4 r1 = h1f4[(size_t)s1 * 4 + q];
        float4 r2 = h1f4[(size_t)s2 * 4 + q];
        float4 r3 = h1f4[(size_t)s3 * 4 + q];
        float f0[8], f1[8], f2[8], f3[8];
        unpack8(r0, f0); unpack8(r1, f1); unpack8(r2, f2); unpack8(r3, f3);
#pragma unroll
        for (int i = 0; i < 8; i++) acc[i] += (f0[i] + f1[i]) + (f2[i] + f3[i]);
    }
    for (; j < cnt; j++) {
        float4 r0 = h1f4[(size_t)lst[j] * 4 + q];
        float f0[8]; unpack8(r0, f0);
#pragma unroll
        for (int i = 0; i < 8; i++) acc[i] += f0[i];
    }
    float hs[8];
    { float4 rs = h1f4[(size_t)n * 4 + q]; unpack8(rs, hs); }
    float di = u0[n].w;
    float g[8];
#pragma unroll
    for (int i = 0; i < 8; i++) {
        int jj = 8 * q + i;
        g[i] = (jj < 29) ? (acc[i] + hs[i]) * di   // di*(sum_nbr + self)
                         : hs[i];                  // A_hat·inp (self-stash)
    }
    float p29[29];
#pragma unroll
    for (int kk = 0; kk < 29; kk++) p29[kk] = 0.f;
#pragma unroll
    for (int i = 0; i < 8; i++) {
        float gi = g[i];
        const float* wr = &W2l[(8 * q + i) * 29];
#pragma unroll
        for (int kk = 0; kk < 29; kk++) p29[kk] = fmaf(gi, wr[kk], p29[kk]);
    }
#pragma unroll
    for (int kk = 0; kk < 29; kk++) {
        p29[kk] += __shfl_xor(p29[kk], 1, 64);
        p29[kk] += __shfl_xor(p29[kk], 2, 64);
    }
    if (q == 0) {
        float z = 0.0f;
#pragma unroll
        for (int kk = 0; kk < 29; kk++)
            z = fmaf(fmaxf(p29[kk] + b2[kk], 0.0f), W3[kk], z);
        z = fmaf(x[2 * n], W3[29], z);
        z = fmaf(x[2 * n + 1], W3[30], z);
        z = fmaf(y1[n], W3[31], z);
        zs[n]  = __float2half_rn(z * di);
        out[n] = fmaf(z * di, di, b3[0]);  // self + bias; neighbor sum added by pull3
    }
}

// Layer-3 pull (2B fp16 gathers from 1MB L2-resident zs) + final scale.
__global__ void pull3_kernel(const __half* __restrict__ zs, const float4* __restrict__ u0,
                             const unsigned int* __restrict__ rowdeg,
                             const unsigned int* __restrict__ ebuf2,
                             float* __restrict__ out, int N) {
    int n = blockIdx.x * blockDim.x + threadIdx.x;
    if (n >= N) return;
    unsigned int rd = rowdeg[n];
    const unsigned int* lst = ebuf2 + (size_t)(n >> BSH2) * CAPB + (rd & 0xFFFFu);
    unsigned int cnt = rd >> 16;
    float s = 0.f;
    unsigned int j = 0;
    for (; j + 4 <= cnt; j += 4) {
        unsigned int i0 = __builtin_nontemporal_load(lst + j);
        unsigned int i1 = __builtin_nontemporal_load(lst + j + 1);
        unsigned int i2 = __builtin_nontemporal_load(lst + j + 2);
        unsigned int i3 = __builtin_nontemporal_load(lst + j + 3);
        s += (__half2float(zs[i0]) + __half2float(zs[i1]))
           + (__half2float(zs[i2]) + __half2float(zs[i3]));
    }
    for (; j < cnt; j++) s += __half2float(zs[lst[j]]);
    out[n] += s * u0[n].w;
}

extern "C" void kernel_launch(void* const* d_in, const int* in_sizes, int n_in,
                              void* d_out, int out_size, void* d_ws, size_t ws_size,
                              hipStream_t stream) {
    const float* x  = (const float*)d_in[0];
    const float* y1 = (const float*)d_in[1];
    const int*   ei = (const int*)d_in[2];
    const float* W1 = (const float*)d_in[3];
    const float* b1 = (const float*)d_in[4];
    const float* W2 = (const float*)d_in[5];
    const float* b2 = (const float*)d_in[6];
    const float* W3 = (const float*)d_in[7];
    const float* b3 = (const float*)d_in[8];
    float* out = (float*)d_out;

    int N = in_sizes[1];
    int E = in_sizes[2] / 2;
    const int* src = ei;
    const int* dst = ei + E;

    size_t Ns = (size_t)N;
    int nb = (N + BN2 - 1) >> BSH2;               // 489 buckets (<=512)
    size_t segtot = (size_t)512 * CAPB;           // ~9.2M entries

    float* ws = (float*)d_ws;
    float4*       u0     = (float4*)ws;                              // 4N floats
    __half*       zs     = (__half*)(ws + 4 * Ns);                   // N halves (N floats rsvd)
    unsigned int* rowdeg = (unsigned int*)(ws + 5 * Ns);             // N
    uint2*        u0h    = (uint2*)(ws + 6 * Ns);                    // 2N floats
    unsigned int* gcur   = (unsigned int*)(ws + 8 * Ns);             // 512
    unsigned int* deg    = gcur + 512;                               // N
    unsigned int* ebuf   = deg + Ns;                                 // segtot
    unsigned int* ebuf2  = ebuf + segtot;                            // segtot
    uint4*        h1s    = (uint4*)(ebuf2 + segtot);                 // 16N floats (fp16 rows)

    // zero gcur + deg in one shot (contiguous)
    hipMemsetAsync(gcur, 0, (512 + Ns) * sizeof(unsigned int), stream);

    const int gS = (E + SPLIT_CH - 1) / SPLIT_CH;
    const int gN = (N + 255) / 256;
    const int g4 = (4 * N + 255) / 256;
    split_kernel <<<gS, 512, 0, stream>>>(src, dst, gcur, deg, ebuf, E);
    prep_kernel  <<<gN, 256, 0, stream>>>(deg, x, y1, u0, u0h, N);
    build2_kernel<<<nb, 1024, 0, stream>>>(gcur, ebuf, u0, u0h, W1, b1,
                                           rowdeg, ebuf2, h1s, N);
    pull2_kernel <<<g4, 256, 0, stream>>>((const float4*)h1s, rowdeg, ebuf2, u0,
                                          x, y1, W2, b2, W3, b3, zs, out, N);
    pull3_kernel <<<gN, 256, 0, stream>>>(zs, u0, rowdeg, ebuf2, out, N);
}

// Round 6
// 446.413 us; speedup vs baseline: 1.6338x; 1.6338x over previous
//
#include <hip/hip_runtime.h>
#include <hip/hip_fp16.h>

// GCN 3-layer, N=500000, E=8000000 — two-level binned CSR + register-pull.
//
// Algebra (aggregation commutes with linear maps):
//   L1: (A_hat @ inp) @ W1          -> 3-float walk of fp16 u0h (fused into build2)
//   L2: [A_hat h1, A_hat inp] @ W2  -> 29-float pull of fp16 h1s rows (fused W2/W3)
//   L3: A_hat (h' @ W3)             -> 1-half pull of fp16 zs (1MB, L2-resident)
// A_hat v = dinv * (sum_nbr(dinv*v) + dinv*v_self)  (pre/post scale).
//
// LESSON (R8, R10 prev session): per-edge LDS float atomics lose to register pulls.
// LESSON (R1): persistent-grid pull2 blew VGPR (occ 11%); src-chunk-sort gave
// zero FETCH reduction (no coherent window at deg~16).
// LESSON (R2): deeper MLP null -> pull2 is REQUEST-RATE-bound on random 64B
// gathers (~3.4TB/s fabric ceiling); byte-minimal. FROZEN at R0 form (~152us).
// LESSON (R2): NT hints belong on STREAMS, not on reuse paths.
// LESSON (R4): __builtin_nontemporal_* rejects HIP_vector_type; use ext_vector.
// LESSON (R5): 8M random global atomicAdds = catastrophe (split 95->329us,
// WRITE_SIZE 33->293MB): device-scope RMW dirties a random 64B line each.
// Degree info must come from the binned hist (build1), never per-edge atomics.
// THIS ROUND: revert to R3 structure (431us) + NT-stream discipline in
// build1/build2 so the walk's only L2-allocating traffic is the 4MB u0h
// gather table -> it becomes L2-resident during the walk.
//
// Passes: split (512thr/8192-edge blocks: in-LDS counting sort -> full-line flush)
//   -> build1 (1 WG/bucket: hist -> wave-scan -> rowdeg/u0/u0h; all NT except LDS)
//   -> build2 (1 WG/bucket: single-pass in-LDS node-sort (full bucket in LDS)
//      -> NT flush; then 2-lane/node register walk x2 rounds gathers u0h
//      (PLAIN loads — the one L2-resident path) + W1/relu -> fp16 h1s (NT))
//   -> pull2 (4 lanes/node register pull of 64B h1s rows, fused W2/relu/W3)
//   -> pull3 (1 thread/node pull of fp16 zs + final scale)

#define CAPB       17920     // per-bucket capacity: mean 16384, sigma 128 (+12 sigma)
#define BSH2       10        // 1024-node coarse buckets
#define BN2        1024
#define PACK_SHIFT 19        // src < 2^19 = 524288 > N
#define PACK_MASK  0x7FFFFu
#define SPLIT_CH   8192      // edges per split block (16/thread, 512 threads)
#define DEST_CAP   17408     // full-bucket LDS staging: mean+8sigma (68KB)

typedef int v4i __attribute__((ext_vector_type(4)));
typedef float v4f __attribute__((ext_vector_type(4)));
typedef unsigned int v4u __attribute__((ext_vector_type(4)));
typedef unsigned int v2u __attribute__((ext_vector_type(2)));

__global__ __launch_bounds__(512) void split_kernel(
    const int* __restrict__ src, const int* __restrict__ dst,
    unsigned int* __restrict__ gcur, unsigned int* __restrict__ ebuf, int E) {
    __shared__ unsigned int hist[512];      // counts -> running cursors
    __shared__ unsigned int delta[512];     // gbase - local_excl_base
    __shared__ unsigned int wsum[8];        // per-wave scan partials
    __shared__ unsigned int tots;
    __shared__ unsigned int staged[SPLIT_CH];     // 32KB
    __shared__ unsigned short bid[SPLIT_CH];      // 16KB
    int tid = threadIdx.x;
    long long base = (long long)blockIdx.x * SPLIT_CH;
    hist[tid] = 0;
    __syncthreads();
    unsigned int s[16], d[16];
    if (base + SPLIT_CH <= E) {          // full chunk: int4 nontemporal loads
        const v4i* s4 = (const v4i*)(src + base);
        const v4i* d4 = (const v4i*)(dst + base);
#pragma unroll
        for (int i = 0; i < 4; i++) {
            v4i sv = __builtin_nontemporal_load(s4 + tid + 512 * i);
            v4i dv = __builtin_nontemporal_load(d4 + tid + 512 * i);
            s[4 * i + 0] = (unsigned int)sv.x; d[4 * i + 0] = (unsigned int)dv.x;
            s[4 * i + 1] = (unsigned int)sv.y; d[4 * i + 1] = (unsigned int)dv.y;
            s[4 * i + 2] = (unsigned int)sv.z; d[4 * i + 2] = (unsigned int)dv.z;
            s[4 * i + 3] = (unsigned int)sv.w; d[4 * i + 3] = (unsigned int)dv.w;
        }
#pragma unroll
        for (int i = 0; i < 16; i++) atomicAdd(&hist[d[i] >> BSH2], 1u);
    } else {                              // tail chunk: scalar with bounds
#pragma unroll
        for (int i = 0; i < 16; i++) {
            long long e = base + tid + 512 * i;
            bool ok = e < E;
            s[i] = ok ? (unsigned int)src[e] : 0u;
            d[i] = ok ? (unsigned int)dst[e] : 0xFFFFFFFFu;
            if (ok) atomicAdd(&hist[d[i] >> BSH2], 1u);
        }
    }
    __syncthreads();
    unsigned int c = hist[tid];
    // wave-shuffle inclusive scan (6 steps), then serial scan of 8 wave sums
    unsigned int v = c;
#pragma unroll
    for (int off = 1; off < 64; off <<= 1) {
        unsigned int t = __shfl_up(v, off, 64);
        if ((tid & 63) >= off) v += t;
    }
    int wv = tid >> 6;
    if ((tid & 63) == 63) wsum[wv] = v;
    __syncthreads();
    if (tid == 0) {
        unsigned int r = 0;
#pragma unroll
        for (int i = 0; i < 8; i++) { unsigned int t = wsum[i]; wsum[i] = r; r += t; }
        tots = r;
    }
    __syncthreads();
    unsigned int excl = v + wsum[wv] - c;      // exclusive prefix
    unsigned int gb = c ? atomicAdd(&gcur[tid], c) : 0u;
    delta[tid] = gb - excl;
    hist[tid] = excl;                     // running cursor
    __syncthreads();
#pragma unroll
    for (int i = 0; i < 16; i++) {
        if (d[i] != 0xFFFFFFFFu) {
            unsigned int bb = d[i] >> BSH2;
            unsigned int pos = atomicAdd(&hist[bb], 1u);
            staged[pos] = s[i] | ((d[i] & (BN2 - 1)) << PACK_SHIFT);
            bid[pos] = (unsigned short)bb;
        }
    }
    __syncthreads();
    unsigned int tot = tots;
    for (unsigned int i = tid; i < tot; i += 512) {   // mostly-consecutive full lines
        unsigned int bb = bid[i];
        unsigned int rel = delta[bb] + i;             // position within bucket
        if (rel < CAPB)
            __builtin_nontemporal_store(staged[i], &ebuf[(size_t)bb * CAPB + rel]);
    }
}

// build1: one WG per 1024-node bucket — hist -> wave-scan -> rowdeg/u0/u0h.
// u0 = {inp*di, di} fp32; u0h = {x0*di, x1*di, y1*di, 0} fp16 (4MB gather table);
// rowdeg = off | deg<<16 (off < CAPB < 2^16).
// All global accesses NT (streams; u0h is refilled cold by build2's walk — 4MB).
__global__ __launch_bounds__(1024) void build1_kernel(
    const unsigned int* __restrict__ gcur, const unsigned int* __restrict__ ebuf,
    const float* __restrict__ x, const float* __restrict__ y1,
    unsigned int* __restrict__ rowdeg, float4* __restrict__ u0,
    uint2* __restrict__ u0h, int N) {
    __shared__ unsigned int hist[BN2];   // 4KB
    __shared__ unsigned int wsum[16];
    int b = blockIdx.x, tid = threadIdx.x;
    hist[tid] = 0;
    unsigned int T = gcur[b]; if (T > CAPB) T = CAPB;
    const unsigned int* seg = ebuf + (size_t)b * CAPB;
    __syncthreads();
    for (unsigned int f = tid; f < T; f += 1024)
        atomicAdd(&hist[__builtin_nontemporal_load(seg + f) >> PACK_SHIFT], 1u);
    __syncthreads();
    unsigned int cnt = hist[tid];
    unsigned int v = cnt;
#pragma unroll
    for (int off = 1; off < 64; off <<= 1) {
        unsigned int t = __shfl_up(v, off, 64);
        if ((tid & 63) >= off) v += t;
    }
    int wv = tid >> 6;
    if ((tid & 63) == 63) wsum[wv] = v;
    __syncthreads();
    if (tid == 0) {
        unsigned int r = 0;
#pragma unroll
        for (int i = 0; i < 16; i++) { unsigned int t = wsum[i]; wsum[i] = r; r += t; }
    }
    __syncthreads();
    unsigned int base = v + wsum[wv] - cnt;      // exclusive
    int n = (b << BSH2) + tid;
    if (n < N) {
        __builtin_nontemporal_store(base | (cnt << 16), &rowdeg[n]);
        float di = rsqrtf((float)cnt + 1.0f);
        float v0 = x[2 * n] * di, v1 = x[2 * n + 1] * di, v2 = y1[n] * di;
        v4f uv; uv.x = v0; uv.y = v1; uv.z = v2; uv.w = di;
        __builtin_nontemporal_store(uv, (v4f*)&u0[n]);
        union { __half2 h2[2]; v2u u; } pk;
        pk.h2[0] = __floats2half2_rn(v0, v1);
        pk.h2[1] = __floats2half2_rn(v2, 0.f);
        __builtin_nontemporal_store(pk.u, (v2u*)&u0h[n]);
    }
}

// Fetch one sorted list entry: LDS dest if staged, else already-written seg2.
__device__ __forceinline__ unsigned int sfetch2(const unsigned int* dest,
                                                const unsigned int* seg2,
                                                unsigned int j) {
    return (j < DEST_CAP) ? dest[j] : seg2[j];
}

// Walk one node with 2 paired lanes (q = tid&1, pair tid^1): gather u0h[src]
// over [o,e), reduce via shfl, run W1/relu epilogue, store 64B fp16 row (NT).
// u0h loads are PLAIN — the one access we want L2 to retain; during the walk
// it is also the ONLY L2-allocating access (everything else NT) -> residency.
__device__ __forceinline__ void walk_node(
    int gn, int q, unsigned int o, unsigned int e,
    const unsigned int* __restrict__ dest, const unsigned int* __restrict__ seg2,
    const uint2* __restrict__ u0h, const float4* __restrict__ u0,
    const float* __restrict__ W1, const float* __restrict__ b1,
    uint4* __restrict__ h1s) {
    unsigned int cnt = e - o;
    unsigned int hcnt = cnt >> 1;
    unsigned int j0 = o + (q ? hcnt : 0), j1 = q ? e : o + hcnt;
    v4f u = __builtin_nontemporal_load((const v4f*)&u0[gn]);
    float sx = q ? 0.f : u.x, sy = q ? 0.f : u.y, sz = q ? 0.f : u.z;
    unsigned int j = j0;
    for (; j + 4 <= j1; j += 4) {
        unsigned int i0 = sfetch2(dest, seg2, j);
        unsigned int i1 = sfetch2(dest, seg2, j + 1);
        unsigned int i2 = sfetch2(dest, seg2, j + 2);
        unsigned int i3 = sfetch2(dest, seg2, j + 3);
        union { uint2 u; __half2 h[2]; } g0, g1, g2, g3;
        g0.u = u0h[i0]; g1.u = u0h[i1]; g2.u = u0h[i2]; g3.u = u0h[i3];
        float2 a0 = __half22float2(g0.h[0]), c0 = __half22float2(g0.h[1]);
        float2 a1 = __half22float2(g1.h[0]), c1 = __half22float2(g1.h[1]);
        float2 a2 = __half22float2(g2.h[0]), c2 = __half22float2(g2.h[1]);
        float2 a3 = __half22float2(g3.h[0]), c3 = __half22float2(g3.h[1]);
        sx += (a0.x + a1.x) + (a2.x + a3.x);
        sy += (a0.y + a1.y) + (a2.y + a3.y);
        sz += (c0.x + c1.x) + (c2.x + c3.x);
    }
    for (; j < j1; j++) {
        union { uint2 u; __half2 h[2]; } g;
        g.u = u0h[sfetch2(dest, seg2, j)];
        float2 a = __half22float2(g.h[0]);
        sx += a.x; sy += a.y; sz += __half2float(g.h[1].x);
    }
    sx += __shfl_xor(sx, 1, 64);      // pair tid^1 = same node
    sy += __shfl_xor(sy, 1, 64);
    sz += __shfl_xor(sz, 1, 64);
    float di = u.w;
    float a0 = sx * di, a1 = sy * di, a2 = sz * di;
    float hv[16];
#pragma unroll
    for (int i = 0; i < 16; i++) {
        int k = 16 * q + i;
        if (k < 29) {
            float vv = fmaf(a0, W1[k], fmaf(a1, W1[29 + k], fmaf(a2, W1[58 + k], b1[k])));
            hv[i] = fmaxf(vv, 0.0f) * di;   // pre-scaled for next aggregation
        } else {
            hv[i] = (k == 29) ? a0 : (k == 30) ? a1 : a2;   // stash A_hat·inp
        }
    }
    union { __half2 h2[8]; v4u u4[2]; } pk;
#pragma unroll
    for (int i = 0; i < 8; i++) pk.h2[i] = __floats2half2_rn(hv[2 * i], hv[2 * i + 1]);
    v4u* row = (v4u*)(h1s + (size_t)gn * 4 + 2 * q);
    __builtin_nontemporal_store(pk.u4[0], row);
    __builtin_nontemporal_store(pk.u4[1], row + 1);
}

// build2: single-pass in-LDS node-sort (full bucket staged in dest[68KB])
// -> sequential NT flush to ebuf2 -> 2 walk rounds (2 lanes/node x 512 nodes)
// gathering u0h + layer-1 W1/relu epilogue -> fp16 h1s (NT).
// h1s[n][0..28] = relu(W1^T a + b1)*di, [29..31] = a = A_hat·inp (raw).
// LDS: cur 4KB + base2 4KB + dest 68KB = 76KB -> 2 WG/CU.
__global__ __launch_bounds__(1024) void build2_kernel(
    const unsigned int* __restrict__ gcur, const unsigned int* __restrict__ ebuf,
    const unsigned int* __restrict__ rowdeg, const float4* __restrict__ u0,
    const uint2* __restrict__ u0h,
    const float* __restrict__ W1, const float* __restrict__ b1,
    unsigned int* __restrict__ ebuf2, uint4* __restrict__ h1s, int N) {
    __shared__ unsigned int cur[BN2];        // 4KB running cursors (absolute)
    __shared__ unsigned int base2[BN2 + 1];  // 4KB per-node offsets for the walk
    __shared__ unsigned int dest[DEST_CAP];  // 68KB full-bucket staging
    int b = blockIdx.x, tid = threadIdx.x;
    int gn0 = (b << BSH2);
    int n = gn0 + tid;
    unsigned int T = gcur[b]; if (T > CAPB) T = CAPB;
    unsigned int off = (n < N) ? (rowdeg[n] & 0xFFFFu) : T;
    cur[tid] = off; base2[tid] = off;
    if (tid == 0) base2[BN2] = T;
    const unsigned int* seg = ebuf + (size_t)b * CAPB;
    unsigned int* seg2 = ebuf2 + (size_t)b * CAPB;
    __syncthreads();
    // single-pass scatter: all nodes' records into dest (overflow -> seg2 direct)
    for (unsigned int f = tid; f < T; f += 1024) {
        unsigned int p = __builtin_nontemporal_load(seg + f);
        unsigned int dloc = p >> PACK_SHIFT;
        unsigned int pos = atomicAdd(&cur[dloc], 1u);
        unsigned int s = p & PACK_MASK;
        if (pos < DEST_CAP) dest[pos] = s;
        else                seg2[pos] = s;       // essentially never (T<=mean+8s)
    }
    __syncthreads();
    // sequential full-line NT flush (dest read-only from here; flush range and
    // walk's seg2 fallback range are disjoint)
    unsigned int m = T < DEST_CAP ? T : DEST_CAP;
    for (unsigned int i = tid; i < m; i += 1024)
        __builtin_nontemporal_store(dest[i], &seg2[i]);
    // fused layer-1 walk: 2 threads/node, 2 rounds of 512 nodes
    int q = tid & 1;
    int l0 = tid >> 1;
    int gnA = gn0 + l0;
    if (gnA < N)
        walk_node(gnA, q, base2[l0], base2[l0 + 1], dest, seg2, u0h, u0, W1, b1, h1s);
    int l1 = l0 + 512;
    int gnB = gn0 + l1;
    if (gnB < N)
        walk_node(gnB, q, base2[l1], base2[l1 + 1], dest, seg2, u0h, u0, W1, b1, h1s);
}

__device__ __forceinline__ void unpack8(float4 r, float* o) {
    union { float4 f; __half2 h[4]; } u; u.f = r;
    float2 a = __half22float2(u.h[0]); o[0] = a.x; o[1] = a.y;
    float2 b = __half22float2(u.h[1]); o[2] = b.x; o[3] = b.y;
    float2 c = __half22float2(u.h[2]); o[4] = c.x; o[5] = c.y;
    float2 d = __half22float2(u.h[3]); o[6] = d.x; o[7] = d.y;
}

// Fused layer-2 pull + W2/relu/W3: 4 lanes/node, 64B row gather/edge,
// unroll-4 register accumulation, LDS W2, shfl_xor reduce. Writes fp16 zs + out.
// FROZEN at R0 form: request-rate-bound on random 64B gathers (R2: deeper MLP
// null; R1: locality sort null). VGPR 40, occupancy ~61%.
__global__ __launch_bounds__(256) void pull2_kernel(
    const float4* __restrict__ h1f4, const unsigned int* __restrict__ rowdeg,
    const unsigned int* __restrict__ ebuf2, const float4* __restrict__ u0,
    const float* __restrict__ x, const float* __restrict__ y1,
    const float* __restrict__ W2, const float* __restrict__ b2,
    const float* __restrict__ W3, const float* __restrict__ b3,
    __half* __restrict__ zs, float* __restrict__ out, int N) {
    __shared__ float W2l[32 * 29];
    for (int i = threadIdx.x; i < 32 * 29; i += 256) W2l[i] = W2[i];
    int t = blockIdx.x * 256 + threadIdx.x;
    int n = t >> 2, q = t & 3;
    __syncthreads();
    if (n >= N) return;
    unsigned int rd = rowdeg[n];
    const unsigned int* lst = ebuf2 + (size_t)(n >> BSH2) * CAPB + (rd & 0xFFFFu);
    unsigned int cnt = rd >> 16;
    float acc[8] = {0.f, 0.f, 0.f, 0.f, 0.f, 0.f, 0.f, 0.f};
    unsigned int j = 0;
    for (; j + 4 <= cnt; j += 4) {        // 4 outstanding 64B row fetches
        unsigned int s0 = lst[j], s1 = lst[j + 1], s2 = lst[j + 2], s3 = lst[j + 3];
        float4 r0 = h1f4[(size_t)s0 * 4 + q];
        float4 r1 = h1f4[(size_t)s1 * 4 + q];
        float4 r2 = h1f4[(size_t)s2 * 4 + q];
        float4 r3 = h1f4[(size_t)s3 * 4 + q];
        float f0[8], f1[8], f2[8], f3[8];
        unpack8(r0, f0); unpack8(r1, f1); unpack8(r2, f2); unpack8(r3, f3);
#pragma unroll
        for (int i = 0; i < 8; i++) acc[i] += (f0[i] + f1[i]) + (f2[i] + f3[i]);
    }
    for (; j < cnt; j++) {
        float4 r0 = h1f4[(size_t)lst[j] * 4 + q];
        float f0[8]; unpack8(r0, f0);
#pragma unroll
        for (int i = 0; i < 8; i++) acc[i] += f0[i];
    }
    float hs[8];
    { float4 rs = h1f4[(size_t)n * 4 + q]; unpack8(rs, hs); }
    float di = u0[n].w;
    float g[8];
#pragma unroll
    for (int i = 0; i < 8; i++) {
        int jj = 8 * q + i;
        g[i] = (jj < 29) ? (acc[i] + hs[i]) * di   // di*(sum_nbr + self)
                         : hs[i];                  // A_hat·inp (self-stash)
    }
    float p29[29];
#pragma unroll
    for (int kk = 0; kk < 29; kk++) p29[kk] = 0.f;
#pragma unroll
    for (int i = 0; i < 8; i++) {
        float gi = g[i];
        const float* wr = &W2l[(8 * q + i) * 29];
#pragma unroll
        for (int kk = 0; kk < 29; kk++) p29[kk] = fmaf(gi, wr[kk], p29[kk]);
    }
#pragma unroll
    for (int kk = 0; kk < 29; kk++) {
        p29[kk] += __shfl_xor(p29[kk], 1, 64);
        p29[kk] += __shfl_xor(p29[kk], 2, 64);
    }
    if (q == 0) {
        float z = 0.0f;
#pragma unroll
        for (int kk = 0; kk < 29; kk++)
            z = fmaf(fmaxf(p29[kk] + b2[kk], 0.0f), W3[kk], z);
        z = fmaf(x[2 * n], W3[29], z);
        z = fmaf(x[2 * n + 1], W3[30], z);
        z = fmaf(y1[n], W3[31], z);
        zs[n]  = __float2half_rn(z * di);
        out[n] = fmaf(z * di, di, b3[0]);  // self + bias; neighbor sum added by pull3
    }
}

// Layer-3 pull (2B fp16 gathers from 1MB L2-resident zs) + final scale.
__global__ void pull3_kernel(const __half* __restrict__ zs, const float4* __restrict__ u0,
                             const unsigned int* __restrict__ rowdeg,
                             const unsigned int* __restrict__ ebuf2,
                             float* __restrict__ out, int N) {
    int n = blockIdx.x * blockDim.x + threadIdx.x;
    if (n >= N) return;
    unsigned int rd = rowdeg[n];
    const unsigned int* lst = ebuf2 + (size_t)(n >> BSH2) * CAPB + (rd & 0xFFFFu);
    unsigned int cnt = rd >> 16;
    float s = 0.f;
    unsigned int j = 0;
    for (; j + 4 <= cnt; j += 4) {
        unsigned int i0 = __builtin_nontemporal_load(lst + j);
        unsigned int i1 = __builtin_nontemporal_load(lst + j + 1);
        unsigned int i2 = __builtin_nontemporal_load(lst + j + 2);
        unsigned int i3 = __builtin_nontemporal_load(lst + j + 3);
        s += (__half2float(zs[i0]) + __half2float(zs[i1]))
           + (__half2float(zs[i2]) + __half2float(zs[i3]));
    }
    for (; j < cnt; j++) s += __half2float(zs[lst[j]]);
    out[n] += s * u0[n].w;
}

extern "C" void kernel_launch(void* const* d_in, const int* in_sizes, int n_in,
                              void* d_out, int out_size, void* d_ws, size_t ws_size,
                              hipStream_t stream) {
    const float* x  = (const float*)d_in[0];
    const float* y1 = (const float*)d_in[1];
    const int*   ei = (const int*)d_in[2];
    const float* W1 = (const float*)d_in[3];
    const float* b1 = (const float*)d_in[4];
    const float* W2 = (const float*)d_in[5];
    const float* b2 = (const float*)d_in[6];
    const float* W3 = (const float*)d_in[7];
    const float* b3 = (const float*)d_in[8];
    float* out = (float*)d_out;

    int N = in_sizes[1];
    int E = in_sizes[2] / 2;
    const int* src = ei;
    const int* dst = ei + E;

    size_t Ns = (size_t)N;
    int nb = (N + BN2 - 1) >> BSH2;               // 489 buckets (<=512)
    size_t segtot = (size_t)512 * CAPB;           // ~9.2M entries

    float* ws = (float*)d_ws;
    float4*       u0     = (float4*)ws;                              // 4N floats
    __half*       zs     = (__half*)(ws + 4 * Ns);                   // N halves (N floats rsvd)
    unsigned int* rowdeg = (unsigned int*)(ws + 5 * Ns);             // N
    uint2*        u0h    = (uint2*)(ws + 6 * Ns);                    // 2N floats
    unsigned int* gcur   = (unsigned int*)(ws + 8 * Ns);             // 512
    unsigned int* ebuf   = gcur + 512;                               // segtot
    unsigned int* ebuf2  = ebuf + segtot;                            // segtot
    uint4*        h1s    = (uint4*)(ebuf2 + segtot);                 // 16N floats (fp16 rows)

    hipMemsetAsync(gcur, 0, 512 * sizeof(unsigned int), stream);

    const int gS = (E + SPLIT_CH - 1) / SPLIT_CH;
    const int gN = (N + 255) / 256;
    const int g4 = (4 * N + 255) / 256;
    split_kernel <<<gS, 512, 0, stream>>>(src, dst, gcur, ebuf, E);
    build1_kernel<<<nb, 1024, 0, stream>>>(gcur, ebuf, x, y1, rowdeg, u0, u0h, N);
    build2_kernel<<<nb, 1024, 0, stream>>>(gcur, ebuf, rowdeg, u0, u0h, W1, b1,
                                           ebuf2, h1s, N);
    pull2_kernel <<<g4, 256, 0, stream>>>((const float4*)h1s, rowdeg, ebuf2, u0,
                                          x, y1, W2, b2, W3, b3, zs, out, N);
    pull3_kernel <<<gN, 256, 0, stream>>>(zs, u0, rowdeg, ebuf2, out, N);
}

// Round 8
// 417.385 us; speedup vs baseline: 1.7474x; 1.0695x over previous
//
#include <hip/hip_runtime.h>
#include <hip/hip_fp16.h>

// GCN 3-layer, N=500000, E=8000000 — two-level binned CSR + register-pull.
//
// Algebra (aggregation commutes with linear maps):
//   L1: (A_hat @ inp) @ W1          -> 3-float walk of fp16 u0h (fused into build2)
//   L2: [A_hat h1, A_hat inp] @ W2  -> 29-float pull of fp16 h1s rows (fused W2/W3)
//   L3: A_hat (h' @ W3)             -> 1-half pull of fp16 zs (1MB, L2-resident)
// A_hat v = dinv * (sum_nbr(dinv*v) + dinv*v_self)  (pre/post scale).
//
// LESSON (prev session): per-edge LDS float atomics lose to register pulls.
// LESSON (R1): persistent-grid pull2 blew VGPR (occ 11%); src-chunk-sort gave
// zero FETCH reduction (no coherent window at deg~16).
// LESSON (R2): deeper MLP null -> pull2 is REQUEST-RATE-bound on random 64B
// gathers (~3.4TB/s beyond-L2 ceiling); byte-minimal. FROZEN at R0 form (152us).
// LESSON (R5): 8M random global atomicAdds = catastrophe (WRITE 33->293MB):
// device-scope RMW dirties a random 64B line each.
// LESSON (R6): NT hints on the build chain REGRESS (+15us) — they destroy
// inter-pass L2 reuse (split ebuf -> build1 -> build2). Keep plain loads/stores.
// LESSON (R7): cooperative-fused kernel FAILED verification with absmax ==
// max|ref| (out never written) — hipLaunchCooperativeKernel silently no-ran
// under the harness (graph capture / co-residency). Lane closed; kernel
// boundaries are the only safe device-wide sync here.
// THIS ROUND: restore R3 (431us, verified) + instruction-issue vectorization:
// uint4 edge reads in build1 hist & build2 scatter, uint4 flush in build2,
// 2-lane/node pull3. Same bytes, ~4x fewer issue slots on the 32MB walks.
//
// Passes: split (512thr/8192-edge blocks: in-LDS counting sort -> line flush)
//   -> build1 (1 WG/bucket: uint4 hist -> wave-scan -> rowdeg/u0/u0h)
//   -> build2 (1 WG/bucket: single-pass in-LDS node-sort (full bucket in LDS,
//      uint4 reads) -> uint4 flush; then 2-lane/node register walk x2 rounds
//      gathers u0h + W1/relu -> fp16 h1s)
//   -> pull2 (4 lanes/node register pull of 64B h1s rows, fused W2/relu/W3)
//   -> pull3 (2 lanes/node pull of fp16 zs + shfl reduce + final scale)

#define CAPB       17920     // per-bucket capacity: mean 16384, sigma 128 (+12 sigma); %4==0
#define BSH2       10        // 1024-node coarse buckets
#define BN2        1024
#define PACK_SHIFT 19        // src < 2^19 = 524288 > N
#define PACK_MASK  0x7FFFFu
#define SPLIT_CH   8192      // edges per split block (16/thread, 512 threads)
#define DEST_CAP   17408     // full-bucket LDS staging: mean+8sigma (68KB)

typedef int v4i __attribute__((ext_vector_type(4)));
typedef unsigned int v4u __attribute__((ext_vector_type(4)));

__global__ __launch_bounds__(512) void split_kernel(
    const int* __restrict__ src, const int* __restrict__ dst,
    unsigned int* __restrict__ gcur, unsigned int* __restrict__ ebuf, int E) {
    __shared__ unsigned int hist[512];      // counts -> running cursors
    __shared__ unsigned int delta[512];     // gbase - local_excl_base
    __shared__ unsigned int wsum[8];        // per-wave scan partials
    __shared__ unsigned int tots;
    __shared__ unsigned int staged[SPLIT_CH];     // 32KB
    __shared__ unsigned short bid[SPLIT_CH];      // 16KB
    int tid = threadIdx.x;
    long long base = (long long)blockIdx.x * SPLIT_CH;
    hist[tid] = 0;
    __syncthreads();
    unsigned int s[16], d[16];
    if (base + SPLIT_CH <= E) {          // full chunk: int4 nontemporal loads
        const v4i* s4 = (const v4i*)(src + base);
        const v4i* d4 = (const v4i*)(dst + base);
#pragma unroll
        for (int i = 0; i < 4; i++) {
            v4i sv = __builtin_nontemporal_load(s4 + tid + 512 * i);
            v4i dv = __builtin_nontemporal_load(d4 + tid + 512 * i);
            s[4 * i + 0] = (unsigned int)sv.x; d[4 * i + 0] = (unsigned int)dv.x;
            s[4 * i + 1] = (unsigned int)sv.y; d[4 * i + 1] = (unsigned int)dv.y;
            s[4 * i + 2] = (unsigned int)sv.z; d[4 * i + 2] = (unsigned int)dv.z;
            s[4 * i + 3] = (unsigned int)sv.w; d[4 * i + 3] = (unsigned int)dv.w;
        }
#pragma unroll
        for (int i = 0; i < 16; i++) atomicAdd(&hist[d[i] >> BSH2], 1u);
    } else {                              // tail chunk: scalar with bounds
#pragma unroll
        for (int i = 0; i < 16; i++) {
            long long e = base + tid + 512 * i;
            bool ok = e < E;
            s[i] = ok ? (unsigned int)src[e] : 0u;
            d[i] = ok ? (unsigned int)dst[e] : 0xFFFFFFFFu;
            if (ok) atomicAdd(&hist[d[i] >> BSH2], 1u);
        }
    }
    __syncthreads();
    unsigned int c = hist[tid];
    // wave-shuffle inclusive scan (6 steps), then serial scan of 8 wave sums
    unsigned int v = c;
#pragma unroll
    for (int off = 1; off < 64; off <<= 1) {
        unsigned int t = __shfl_up(v, off, 64);
        if ((tid & 63) >= off) v += t;
    }
    int wv = tid >> 6;
    if ((tid & 63) == 63) wsum[wv] = v;
    __syncthreads();
    if (tid == 0) {
        unsigned int r = 0;
#pragma unroll
        for (int i = 0; i < 8; i++) { unsigned int t = wsum[i]; wsum[i] = r; r += t; }
        tots = r;
    }
    __syncthreads();
    unsigned int excl = v + wsum[wv] - c;      // exclusive prefix
    unsigned int gb = c ? atomicAdd(&gcur[tid], c) : 0u;
    delta[tid] = gb - excl;
    hist[tid] = excl;                     // running cursor
    __syncthreads();
#pragma unroll
    for (int i = 0; i < 16; i++) {
        if (d[i] != 0xFFFFFFFFu) {
            unsigned int bb = d[i] >> BSH2;
            unsigned int pos = atomicAdd(&hist[bb], 1u);
            staged[pos] = s[i] | ((d[i] & (BN2 - 1)) << PACK_SHIFT);
            bid[pos] = (unsigned short)bb;
        }
    }
    __syncthreads();
    unsigned int tot = tots;
    for (unsigned int i = tid; i < tot; i += 512) {   // mostly-consecutive full lines
        unsigned int bb = bid[i];
        unsigned int rel = delta[bb] + i;             // position within bucket
        if (rel < CAPB) ebuf[(size_t)bb * CAPB + rel] = staged[i];
    }
}

// build1: one WG per 1024-node bucket — uint4 hist -> wave-scan -> rowdeg/u0/u0h.
// u0 = {inp*di, di} fp32; u0h = {x0*di, x1*di, y1*di, 0} fp16 (4MB gather table);
// rowdeg = off | deg<<16 (off < CAPB < 2^16). Plain loads (L2 reuse, R6 lesson).
__global__ __launch_bounds__(1024) void build1_kernel(
    const unsigned int* __restrict__ gcur, const unsigned int* __restrict__ ebuf,
    const float* __restrict__ x, const float* __restrict__ y1,
    unsigned int* __restrict__ rowdeg, float4* __restrict__ u0,
    uint2* __restrict__ u0h, int N) {
    __shared__ unsigned int hist[BN2];   // 4KB
    __shared__ unsigned int wsum[16];
    int b = blockIdx.x, tid = threadIdx.x;
    hist[tid] = 0;
    unsigned int T = gcur[b]; if (T > CAPB) T = CAPB;
    const unsigned int* seg = ebuf + (size_t)b * CAPB;   // 16B aligned (CAPB%4==0)
    __syncthreads();
    unsigned int T4 = T & ~3u;
    for (unsigned int f = 4 * tid; f < T4; f += 4096) {
        v4u p = *(const v4u*)(seg + f);
        atomicAdd(&hist[p.x >> PACK_SHIFT], 1u);
        atomicAdd(&hist[p.y >> PACK_SHIFT], 1u);
        atomicAdd(&hist[p.z >> PACK_SHIFT], 1u);
        atomicAdd(&hist[p.w >> PACK_SHIFT], 1u);
    }
    for (unsigned int f = T4 + tid; f < T; f += 1024)
        atomicAdd(&hist[seg[f] >> PACK_SHIFT], 1u);
    __syncthreads();
    unsigned int cnt = hist[tid];
    unsigned int v = cnt;
#pragma unroll
    for (int off = 1; off < 64; off <<= 1) {
        unsigned int t = __shfl_up(v, off, 64);
        if ((tid & 63) >= off) v += t;
    }
    int wv = tid >> 6;
    if ((tid & 63) == 63) wsum[wv] = v;
    __syncthreads();
    if (tid == 0) {
        unsigned int r = 0;
#pragma unroll
        for (int i = 0; i < 16; i++) { unsigned int t = wsum[i]; wsum[i] = r; r += t; }
    }
    __syncthreads();
    unsigned int base = v + wsum[wv] - cnt;      // exclusive
    int n = (b << BSH2) + tid;
    if (n < N) {
        rowdeg[n] = base | (cnt << 16);
        float di = rsqrtf((float)cnt + 1.0f);
        float v0 = x[2 * n] * di, v1 = x[2 * n + 1] * di, v2 = y1[n] * di;
        u0[n] = make_float4(v0, v1, v2, di);
        union { __half2 h2[2]; uint2 u; } pk;
        pk.h2[0] = __floats2half2_rn(v0, v1);
        pk.h2[1] = __floats2half2_rn(v2, 0.f);
        u0h[n] = pk.u;
    }
}

// Fetch one sorted list entry: LDS dest if staged, else overflow in seg2.
__device__ __forceinline__ unsigned int sfetch2(const unsigned int* dest,
                                                const unsigned int* seg2,
                                                unsigned int j) {
    return (j < DEST_CAP) ? dest[j] : seg2[j];
}

// Walk one node with 2 paired lanes (q = tid&1, pair tid^1): gather u0h[src]
// over [o,e), reduce via shfl, run W1/relu epilogue, store 64B fp16 row.
__device__ __forceinline__ void walk_node(
    int gn, int q, unsigned int o, unsigned int e,
    const unsigned int* __restrict__ dest, const unsigned int* __restrict__ seg2,
    const uint2* __restrict__ u0h, const float4* __restrict__ u0,
    const float* __restrict__ W1, const float* __restrict__ b1,
    uint4* __restrict__ h1s) {
    unsigned int cnt = e - o;
    unsigned int hcnt = cnt >> 1;
    unsigned int j0 = o + (q ? hcnt : 0), j1 = q ? e : o + hcnt;
    float4 u = u0[gn];
    float sx = q ? 0.f : u.x, sy = q ? 0.f : u.y, sz = q ? 0.f : u.z;
    unsigned int j = j0;
    for (; j + 4 <= j1; j += 4) {
        unsigned int i0 = sfetch2(dest, seg2, j);
        unsigned int i1 = sfetch2(dest, seg2, j + 1);
        unsigned int i2 = sfetch2(dest, seg2, j + 2);
        unsigned int i3 = sfetch2(dest, seg2, j + 3);
        union { uint2 u; __half2 h[2]; } g0, g1, g2, g3;
        g0.u = u0h[i0]; g1.u = u0h[i1]; g2.u = u0h[i2]; g3.u = u0h[i3];
        float2 a0 = __half22float2(g0.h[0]), c0 = __half22float2(g0.h[1]);
        float2 a1 = __half22float2(g1.h[0]), c1 = __half22float2(g1.h[1]);
        float2 a2 = __half22float2(g2.h[0]), c2 = __half22float2(g2.h[1]);
        float2 a3 = __half22float2(g3.h[0]), c3 = __half22float2(g3.h[1]);
        sx += (a0.x + a1.x) + (a2.x + a3.x);
        sy += (a0.y + a1.y) + (a2.y + a3.y);
        sz += (c0.x + c1.x) + (c2.x + c3.x);
    }
    for (; j < j1; j++) {
        union { uint2 u; __half2 h[2]; } g;
        g.u = u0h[sfetch2(dest, seg2, j)];
        float2 a = __half22float2(g.h[0]);
        sx += a.x; sy += a.y; sz += __half2float(g.h[1].x);
    }
    sx += __shfl_xor(sx, 1, 64);      // pair tid^1 = same node
    sy += __shfl_xor(sy, 1, 64);
    sz += __shfl_xor(sz, 1, 64);
    float di = u.w;
    float a0 = sx * di, a1 = sy * di, a2 = sz * di;
    float hv[16];
#pragma unroll
    for (int i = 0; i < 16; i++) {
        int k = 16 * q + i;
        if (k < 29) {
            float vv = fmaf(a0, W1[k], fmaf(a1, W1[29 + k], fmaf(a2, W1[58 + k], b1[k])));
            hv[i] = fmaxf(vv, 0.0f) * di;   // pre-scaled for next aggregation
        } else {
            hv[i] = (k == 29) ? a0 : (k == 30) ? a1 : a2;   // stash A_hat·inp
        }
    }
    union { __half2 h2[8]; uint4 u4[2]; } pk;
#pragma unroll
    for (int i = 0; i < 8; i++) pk.h2[i] = __floats2half2_rn(hv[2 * i], hv[2 * i + 1]);
    uint4* row = h1s + (size_t)gn * 4 + 2 * q;
    row[0] = pk.u4[0];
    row[1] = pk.u4[1];
}

// build2: single-pass in-LDS node-sort (full bucket staged in dest[68KB], uint4
// reads) -> uint4 flush to ebuf2 -> 2 walk rounds (2 lanes/node x 512 nodes)
// gathering u0h + layer-1 W1/relu epilogue -> fp16 h1s.
// h1s[n][0..28] = relu(W1^T a + b1)*di, [29..31] = a = A_hat·inp (raw).
// LDS: cur 4KB + base2 4KB + dest 68KB = 76KB -> 2 WG/CU.
__global__ __launch_bounds__(1024) void build2_kernel(
    const unsigned int* __restrict__ gcur, const unsigned int* __restrict__ ebuf,
    const unsigned int* __restrict__ rowdeg, const float4* __restrict__ u0,
    const uint2* __restrict__ u0h,
    const float* __restrict__ W1, const float* __restrict__ b1,
    unsigned int* __restrict__ ebuf2, uint4* __restrict__ h1s, int N) {
    __shared__ unsigned int cur[BN2];        // 4KB running cursors (absolute)
    __shared__ unsigned int base2[BN2 + 1];  // 4KB per-node offsets for the walk
    __shared__ unsigned int dest[DEST_CAP];  // 68KB full-bucket staging
    int b = blockIdx.x, tid = threadIdx.x;
    int gn0 = (b << BSH2);
    int n = gn0 + tid;
    unsigned int T = gcur[b]; if (T > CAPB) T = CAPB;
    unsigned int off = (n < N) ? (rowdeg[n] & 0xFFFFu) : T;
    cur[tid] = off; base2[tid] = off;
    if (tid == 0) base2[BN2] = T;
    const unsigned int* seg = ebuf + (size_t)b * CAPB;   // 16B aligned
    unsigned int* seg2 = ebuf2 + (size_t)b * CAPB;       // 16B aligned
    __syncthreads();
    // single-pass scatter (uint4 reads): records node-sorted into dest
    // (overflow -> seg2 direct; essentially never, T <= mean+8sigma)
    unsigned int T4 = T & ~3u;
    for (unsigned int f = 4 * tid; f < T4; f += 4096) {
        v4u p = *(const v4u*)(seg + f);
        {
            unsigned int dl = p.x >> PACK_SHIFT, pos = atomicAdd(&cur[dl], 1u);
            unsigned int sv = p.x & PACK_MASK;
            if (pos < DEST_CAP) dest[pos] = sv; else seg2[pos] = sv;
        }
        {
            unsigned int dl = p.y >> PACK_SHIFT, pos = atomicAdd(&cur[dl], 1u);
            unsigned int sv = p.y & PACK_MASK;
            if (pos < DEST_CAP) dest[pos] = sv; else seg2[pos] = sv;
        }
        {
            unsigned int dl = p.z >> PACK_SHIFT, pos = atomicAdd(&cur[dl], 1u);
            unsigned int sv = p.z & PACK_MASK;
            if (pos < DEST_CAP) dest[pos] = sv; else seg2[pos] = sv;
        }
        {
            unsigned int dl = p.w >> PACK_SHIFT, pos = atomicAdd(&cur[dl], 1u);
            unsigned int sv = p.w & PACK_MASK;
            if (pos < DEST_CAP) dest[pos] = sv; else seg2[pos] = sv;
        }
    }
    for (unsigned int f = T4 + tid; f < T; f += 1024) {
        unsigned int p = seg[f];
        unsigned int dl = p >> PACK_SHIFT, pos = atomicAdd(&cur[dl], 1u);
        unsigned int sv = p & PACK_MASK;
        if (pos < DEST_CAP) dest[pos] = sv; else seg2[pos] = sv;
    }
    __syncthreads();
    // sequential uint4 flush (dest read-only from here; flush range and walk's
    // seg2 fallback range are disjoint)
    unsigned int m = T < DEST_CAP ? T : DEST_CAP;
    unsigned int m4 = m & ~3u;
    for (unsigned int i = 4 * tid; i < m4; i += 4096) {
        v4u w4;
        w4.x = dest[i]; w4.y = dest[i + 1]; w4.z = dest[i + 2]; w4.w = dest[i + 3];
        *(v4u*)(seg2 + i) = w4;
    }
    for (unsigned int i = m4 + tid; i < m; i += 1024) seg2[i] = dest[i];
    // fused layer-1 walk: 2 threads/node, 2 rounds of 512 nodes
    int q = tid & 1;
    int l0 = tid >> 1;
    int gnA = gn0 + l0;
    if (gnA < N)
        walk_node(gnA, q, base2[l0], base2[l0 + 1], dest, seg2, u0h, u0, W1, b1, h1s);
    int l1 = l0 + 512;
    int gnB = gn0 + l1;
    if (gnB < N)
        walk_node(gnB, q, base2[l1], base2[l1 + 1], dest, seg2, u0h, u0, W1, b1, h1s);
}

__device__ __forceinline__ void unpack8(float4 r, float* o) {
    union { float4 f; __half2 h[4]; } u; u.f = r;
    float2 a = __half22float2(u.h[0]); o[0] = a.x; o[1] = a.y;
    float2 b = __half22float2(u.h[1]); o[2] = b.x; o[3] = b.y;
    float2 c = __half22float2(u.h[2]); o[4] = c.x; o[5] = c.y;
    float2 d = __half22float2(u.h[3]); o[6] = d.x; o[7] = d.y;
}

// Fused layer-2 pull + W2/relu/W3: 4 lanes/node, 64B row gather/edge,
// unroll-4 register accumulation, LDS W2, shfl_xor reduce. Writes fp16 zs + out.
// FROZEN at R0 form: request-rate-bound on random 64B gathers (R2: deeper MLP
// null; R1: locality sort null). VGPR 40, occupancy ~61%.
__global__ __launch_bounds__(256) void pull2_kernel(
    const float4* __restrict__ h1f4, const unsigned int* __restrict__ rowdeg,
    const unsigned int* __restrict__ ebuf2, const float4* __restrict__ u0,
    const float* __restrict__ x, const float* __restrict__ y1,
    const float* __restrict__ W2, const float* __restrict__ b2,
    const float* __restrict__ W3, const float* __restrict__ b3,
    __half* __restrict__ zs, float* __restrict__ out, int N) {
    __shared__ float W2l[32 * 29];
    for (int i = threadIdx.x; i < 32 * 29; i += 256) W2l[i] = W2[i];
    int t = blockIdx.x * 256 + threadIdx.x;
    int n = t >> 2, q = t & 3;
    __syncthreads();
    if (n >= N) return;
    unsigned int rd = rowdeg[n];
    const unsigned int* lst = ebuf2 + (size_t)(n >> BSH2) * CAPB + (rd & 0xFFFFu);
    unsigned int cnt = rd >> 16;
    float acc[8] = {0.f, 0.f, 0.f, 0.f, 0.f, 0.f, 0.f, 0.f};
    unsigned int j = 0;
    for (; j + 4 <= cnt; j += 4) {        // 4 outstanding 64B row fetches
        unsigned int s0 = lst[j], s1 = lst[j + 1], s2 = lst[j + 2], s3 = lst[j + 3];
        float4 r0 = h1f4[(size_t)s0 * 4 + q];
        float4 r1 = h1f4[(size_t)s1 * 4 + q];
        float4 r2 = h1f4[(size_t)s2 * 4 + q];
        float4 r3 = h1f4[(size_t)s3 * 4 + q];
        float f0[8], f1[8], f2[8], f3[8];
        unpack8(r0, f0); unpack8(r1, f1); unpack8(r2, f2); unpack8(r3, f3);
#pragma unroll
        for (int i = 0; i < 8; i++) acc[i] += (f0[i] + f1[i]) + (f2[i] + f3[i]);
    }
    for (; j < cnt; j++) {
        float4 r0 = h1f4[(size_t)lst[j] * 4 + q];
        float f0[8]; unpack8(r0, f0);
#pragma unroll
        for (int i = 0; i < 8; i++) acc[i] += f0[i];
    }
    float hs[8];
    { float4 rs = h1f4[(size_t)n * 4 + q]; unpack8(rs, hs); }
    float di = u0[n].w;
    float g[8];
#pragma unroll
    for (int i = 0; i < 8; i++) {
        int jj = 8 * q + i;
        g[i] = (jj < 29) ? (acc[i] + hs[i]) * di   // di*(sum_nbr + self)
                         : hs[i];                  // A_hat·inp (self-stash)
    }
    float p29[29];
#pragma unroll
    for (int kk = 0; kk < 29; kk++) p29[kk] = 0.f;
#pragma unroll
    for (int i = 0; i < 8; i++) {
        float gi = g[i];
        const float* wr = &W2l[(8 * q + i) * 29];
#pragma unroll
        for (int kk = 0; kk < 29; kk++) p29[kk] = fmaf(gi, wr[kk], p29[kk]);
    }
#pragma unroll
    for (int kk = 0; kk < 29; kk++) {
        p29[kk] += __shfl_xor(p29[kk], 1, 64);
        p29[kk] += __shfl_xor(p29[kk], 2, 64);
    }
    if (q == 0) {
        float z = 0.0f;
#pragma unroll
        for (int kk = 0; kk < 29; kk++)
            z = fmaf(fmaxf(p29[kk] + b2[kk], 0.0f), W3[kk], z);
        z = fmaf(x[2 * n], W3[29], z);
        z = fmaf(x[2 * n + 1], W3[30], z);
        z = fmaf(y1[n], W3[31], z);
        zs[n]  = __float2half_rn(z * di);
        out[n] = fmaf(z * di, di, b3[0]);  // self + bias; neighbor sum added by pull3
    }
}

// Layer-3 pull: 2 lanes/node (halved serial walk, latency-bound pass),
// 2B fp16 gathers from 1MB L2-resident zs, shfl reduce + final scale.
__global__ void pull3_kernel(const __half* __restrict__ zs, const float4* __restrict__ u0,
                             const unsigned int* __restrict__ rowdeg,
                             const unsigned int* __restrict__ ebuf2,
                             float* __restrict__ out, int N) {
    int t = blockIdx.x * blockDim.x + threadIdx.x;
    int n = t >> 1, q = t & 1;
    if (n >= N) return;
    unsigned int rd = rowdeg[n];
    const unsigned int* lst = ebuf2 + (size_t)(n >> BSH2) * CAPB + (rd & 0xFFFFu);
    unsigned int cnt = rd >> 16;
    unsigned int h = cnt >> 1;
    unsigned int j0 = q ? h : 0, j1 = q ? cnt : h;
    float s = 0.f;
    unsigned int j = j0;
    for (; j + 4 <= j1; j += 4) {
        unsigned int i0 = __builtin_nontemporal_load(lst + j);
        unsigned int i1 = __builtin_nontemporal_load(lst + j + 1);
        unsigned int i2 = __builtin_nontemporal_load(lst + j + 2);
        unsigned int i3 = __builtin_nontemporal_load(lst + j + 3);
        s += (__half2float(zs[i0]) + __half2float(zs[i1]))
           + (__half2float(zs[i2]) + __half2float(zs[i3]));
    }
    for (; j < j1; j++) s += __half2float(zs[__builtin_nontemporal_load(lst + j)]);
    s += __shfl_xor(s, 1, 64);            // pair tid^1 = same node
    if (q == 0) out[n] += s * u0[n].w;
}

extern "C" void kernel_launch(void* const* d_in, const int* in_sizes, int n_in,
                              void* d_out, int out_size, void* d_ws, size_t ws_size,
                              hipStream_t stream) {
    const float* x  = (const float*)d_in[0];
    const float* y1 = (const float*)d_in[1];
    const int*   ei = (const int*)d_in[2];
    const float* W1 = (const float*)d_in[3];
    const float* b1 = (const float*)d_in[4];
    const float* W2 = (const float*)d_in[5];
    const float* b2 = (const float*)d_in[6];
    const float* W3 = (const float*)d_in[7];
    const float* b3 = (const float*)d_in[8];
    float* out = (float*)d_out;

    int N = in_sizes[1];
    int E = in_sizes[2] / 2;
    const int* src = ei;
    const int* dst = ei + E;

    size_t Ns = (size_t)N;
    int nb = (N + BN2 - 1) >> BSH2;               // 489 buckets (<=512)
    size_t segtot = (size_t)512 * CAPB;           // ~9.2M entries

    float* ws = (float*)d_ws;
    float4*       u0     = (float4*)ws;                              // 4N floats
    __half*       zs     = (__half*)(ws + 4 * Ns);                   // N halves (N floats rsvd)
    unsigned int* rowdeg = (unsigned int*)(ws + 5 * Ns);             // N
    uint2*        u0h    = (uint2*)(ws + 6 * Ns);                    // 2N floats
    unsigned int* gcur   = (unsigned int*)(ws + 8 * Ns);             // 512
    unsigned int* ebuf   = gcur + 512;                               // segtot
    unsigned int* ebuf2  = ebuf + segtot;                            // segtot
    uint4*        h1s    = (uint4*)(ebuf2 + segtot);                 // 16N floats (fp16 rows)

    (void)hipMemsetAsync(gcur, 0, 512 * sizeof(unsigned int), stream);

    const int gS = (E + SPLIT_CH - 1) / SPLIT_CH;
    const int g2 = (2 * N + 255) / 256;
    const int g4 = (4 * N + 255) / 256;
    split_kernel <<<gS, 512, 0, stream>>>(src, dst, gcur, ebuf, E);
    build1_kernel<<<nb, 1024, 0, stream>>>(gcur, ebuf, x, y1, rowdeg, u0, u0h, N);
    build2_kernel<<<nb, 1024, 0, stream>>>(gcur, ebuf, rowdeg, u0, u0h, W1, b1,
                                           ebuf2, h1s, N);
    pull2_kernel <<<g4, 256, 0, stream>>>((const float4*)h1s, rowdeg, ebuf2, u0,
                                          x, y1, W2, b2, W3, b3, zs, out, N);
    pull3_kernel <<<g2, 256, 0, stream>>>(zs, u0, rowdeg, ebuf2, out, N);
}

// Round 9
// 404.638 us; speedup vs baseline: 1.8024x; 1.0315x over previous
//
#include <hip/hip_runtime.h>
#include <hip/hip_fp16.h>

// GCN 3-layer, N=500000, E=8000000 — two-level binned CSR + register-pull.
//
// Algebra (aggregation commutes with linear maps):
//   L1: (A_hat @ inp) @ W1          -> 3-float walk of fp16 u0h (fused into build2)
//   L2: [A_hat h1, A_hat inp] @ W2  -> 29-float pull of fp16 h1s rows (fused W2/W3)
//   L3: A_hat (h' @ W3)             -> 1-half pull of fp16 zs (1MB, L2-resident)
// A_hat v = dinv * (sum_nbr(dinv*v) + dinv*v_self)  (pre/post scale).
//
// LESSON (prev session): per-edge LDS float atomics lose to register pulls.
// LESSON (R1): persistent-grid pull2 blew VGPR (occ 11%); src-chunk-sort gave
// zero FETCH reduction (no coherent window at deg~16).
// LESSON (R2): deeper MLP null -> pull2 is REQUEST-RATE-bound on random 64B
// gathers (~3.4TB/s = random-64B L3/DRAM service ceiling); byte-minimal.
// FROZEN at R0 form (150us).
// LESSON (R5): 8M random global atomicAdds = catastrophe (WRITE 33->293MB):
// device-scope RMW dirties a random 64B line each.
// LESSON (R6): NT hints on the build chain REGRESS (+15us) — they destroy
// inter-pass L2 reuse (split ebuf -> build1 -> build2). Keep plain loads/stores.
// LESSON (R7): cooperative-fused kernel silently no-ran under the harness
// (absmax == max|ref|). Kernel boundaries are the only safe device-wide sync.
// LESSON (R8): issue-vectorization (uint4 walks) -14us; split conflict counter
// shows LDS BANK conflicts are ~4% — build chain is LDS-op-count/phase-bound.
// THIS ROUND: split at SPLIT_CH=16384/1024thr (half the blocks -> half the
// scan/barrier overhead, 2x flush run length); pull3 at 4 lanes/node.
//
// Passes: split (1024thr/16384-edge blocks: in-LDS counting sort -> line flush)
//   -> build1 (1 WG/bucket: uint4 hist -> wave-scan -> rowdeg/u0/u0h)
//   -> build2 (1 WG/bucket: single-pass in-LDS node-sort (full bucket in LDS,
//      uint4 reads) -> uint4 flush; then 2-lane/node register walk x2 rounds
//      gathers u0h + W1/relu -> fp16 h1s)
//   -> pull2 (4 lanes/node register pull of 64B h1s rows, fused W2/relu/W3)
//   -> pull3 (4 lanes/node pull of fp16 zs + shfl reduce + final scale)

#define CAPB       17920     // per-bucket capacity: mean 16384, sigma 128 (+12 sigma); %4==0
#define BSH2       10        // 1024-node coarse buckets
#define BN2        1024
#define PACK_SHIFT 19        // src < 2^19 = 524288 > N
#define PACK_MASK  0x7FFFFu
#define SPLIT_CH   16384     // edges per split block (16/thread, 1024 threads)
#define DEST_CAP   17408     // full-bucket LDS staging: mean+8sigma (68KB)

typedef int v4i __attribute__((ext_vector_type(4)));
typedef unsigned int v4u __attribute__((ext_vector_type(4)));

// split: 1024 threads, 16384 edges/block. LDS: staged 64KB + bid 32KB + aux
// ~4.3KB = ~100KB -> 1 WG/CU (16 waves). Halved block count vs 8192-chunk
// (489 blocks), doubled flush run length (32 words/bucket avg).
__global__ __launch_bounds__(1024) void split_kernel(
    const int* __restrict__ src, const int* __restrict__ dst,
    unsigned int* __restrict__ gcur, unsigned int* __restrict__ ebuf, int E) {
    __shared__ unsigned int hist[512];      // counts -> running cursors
    __shared__ unsigned int delta[512];     // gbase - local_excl_base
    __shared__ unsigned int wsum[8];        // per-wave scan partials
    __shared__ unsigned int tots;
    __shared__ unsigned int staged[SPLIT_CH];     // 64KB
    __shared__ unsigned short bid[SPLIT_CH];      // 32KB
    int tid = threadIdx.x;
    long long base = (long long)blockIdx.x * SPLIT_CH;
    if (tid < 512) hist[tid] = 0;
    __syncthreads();
    unsigned int s[16], d[16];
    if (base + SPLIT_CH <= E) {          // full chunk: int4 nontemporal loads
        const v4i* s4 = (const v4i*)(src + base);
        const v4i* d4 = (const v4i*)(dst + base);
#pragma unroll
        for (int i = 0; i < 4; i++) {
            v4i sv = __builtin_nontemporal_load(s4 + tid + 1024 * i);
            v4i dv = __builtin_nontemporal_load(d4 + tid + 1024 * i);
            s[4 * i + 0] = (unsigned int)sv.x; d[4 * i + 0] = (unsigned int)dv.x;
            s[4 * i + 1] = (unsigned int)sv.y; d[4 * i + 1] = (unsigned int)dv.y;
            s[4 * i + 2] = (unsigned int)sv.z; d[4 * i + 2] = (unsigned int)dv.z;
            s[4 * i + 3] = (unsigned int)sv.w; d[4 * i + 3] = (unsigned int)dv.w;
        }
#pragma unroll
        for (int i = 0; i < 16; i++) atomicAdd(&hist[d[i] >> BSH2], 1u);
    } else {                              // tail chunk: scalar with bounds
#pragma unroll
        for (int i = 0; i < 16; i++) {
            long long e = base + tid + 1024 * i;
            bool ok = e < E;
            s[i] = ok ? (unsigned int)src[e] : 0u;
            d[i] = ok ? (unsigned int)dst[e] : 0xFFFFFFFFu;
            if (ok) atomicAdd(&hist[d[i] >> BSH2], 1u);
        }
    }
    __syncthreads();
    // wave-shuffle inclusive scan over 512 bins (waves 0..7), then serial
    // scan of 8 wave sums. Threads >=512 idle through (hit the barriers).
    unsigned int c = 0, v = 0;
    if (tid < 512) { c = hist[tid]; v = c; }
#pragma unroll
    for (int off = 1; off < 64; off <<= 1) {
        unsigned int t = __shfl_up(v, off, 64);
        if ((tid & 63) >= off) v += t;
    }
    if (tid < 512 && (tid & 63) == 63) wsum[tid >> 6] = v;
    __syncthreads();
    if (tid == 0) {
        unsigned int r = 0;
#pragma unroll
        for (int i = 0; i < 8; i++) { unsigned int t = wsum[i]; wsum[i] = r; r += t; }
        tots = r;
    }
    __syncthreads();
    if (tid < 512) {
        unsigned int excl = v + wsum[tid >> 6] - c;   // exclusive prefix
        unsigned int gb = c ? atomicAdd(&gcur[tid], c) : 0u;
        delta[tid] = gb - excl;
        hist[tid] = excl;                 // running cursor
    }
    __syncthreads();
#pragma unroll
    for (int i = 0; i < 16; i++) {
        if (d[i] != 0xFFFFFFFFu) {
            unsigned int bb = d[i] >> BSH2;
            unsigned int pos = atomicAdd(&hist[bb], 1u);
            staged[pos] = s[i] | ((d[i] & (BN2 - 1)) << PACK_SHIFT);
            bid[pos] = (unsigned short)bb;
        }
    }
    __syncthreads();
    unsigned int tot = tots;
    for (unsigned int i = tid; i < tot; i += 1024) {  // mostly-consecutive full lines
        unsigned int bb = bid[i];
        unsigned int rel = delta[bb] + i;             // position within bucket
        if (rel < CAPB) ebuf[(size_t)bb * CAPB + rel] = staged[i];
    }
}

// build1: one WG per 1024-node bucket — uint4 hist -> wave-scan -> rowdeg/u0/u0h.
// u0 = {inp*di, di} fp32; u0h = {x0*di, x1*di, y1*di, 0} fp16 (4MB gather table);
// rowdeg = off | deg<<16 (off < CAPB < 2^16). Plain loads (L2 reuse, R6 lesson).
__global__ __launch_bounds__(1024) void build1_kernel(
    const unsigned int* __restrict__ gcur, const unsigned int* __restrict__ ebuf,
    const float* __restrict__ x, const float* __restrict__ y1,
    unsigned int* __restrict__ rowdeg, float4* __restrict__ u0,
    uint2* __restrict__ u0h, int N) {
    __shared__ unsigned int hist[BN2];   // 4KB
    __shared__ unsigned int wsum[16];
    int b = blockIdx.x, tid = threadIdx.x;
    hist[tid] = 0;
    unsigned int T = gcur[b]; if (T > CAPB) T = CAPB;
    const unsigned int* seg = ebuf + (size_t)b * CAPB;   // 16B aligned (CAPB%4==0)
    __syncthreads();
    unsigned int T4 = T & ~3u;
    for (unsigned int f = 4 * tid; f < T4; f += 4096) {
        v4u p = *(const v4u*)(seg + f);
        atomicAdd(&hist[p.x >> PACK_SHIFT], 1u);
        atomicAdd(&hist[p.y >> PACK_SHIFT], 1u);
        atomicAdd(&hist[p.z >> PACK_SHIFT], 1u);
        atomicAdd(&hist[p.w >> PACK_SHIFT], 1u);
    }
    for (unsigned int f = T4 + tid; f < T; f += 1024)
        atomicAdd(&hist[seg[f] >> PACK_SHIFT], 1u);
    __syncthreads();
    unsigned int cnt = hist[tid];
    unsigned int v = cnt;
#pragma unroll
    for (int off = 1; off < 64; off <<= 1) {
        unsigned int t = __shfl_up(v, off, 64);
        if ((tid & 63) >= off) v += t;
    }
    int wv = tid >> 6;
    if ((tid & 63) == 63) wsum[wv] = v;
    __syncthreads();
    if (tid == 0) {
        unsigned int r = 0;
#pragma unroll
        for (int i = 0; i < 16; i++) { unsigned int t = wsum[i]; wsum[i] = r; r += t; }
    }
    __syncthreads();
    unsigned int base = v + wsum[wv] - cnt;      // exclusive
    int n = (b << BSH2) + tid;
    if (n < N) {
        rowdeg[n] = base | (cnt << 16);
        float di = rsqrtf((float)cnt + 1.0f);
        float v0 = x[2 * n] * di, v1 = x[2 * n + 1] * di, v2 = y1[n] * di;
        u0[n] = make_float4(v0, v1, v2, di);
        union { __half2 h2[2]; uint2 u; } pk;
        pk.h2[0] = __floats2half2_rn(v0, v1);
        pk.h2[1] = __floats2half2_rn(v2, 0.f);
        u0h[n] = pk.u;
    }
}

// Fetch one sorted list entry: LDS dest if staged, else overflow in seg2.
__device__ __forceinline__ unsigned int sfetch2(const unsigned int* dest,
                                                const unsigned int* seg2,
                                                unsigned int j) {
    return (j < DEST_CAP) ? dest[j] : seg2[j];
}

// Walk one node with 2 paired lanes (q = tid&1, pair tid^1): gather u0h[src]
// over [o,e), reduce via shfl, run W1/relu epilogue, store 64B fp16 row.
__device__ __forceinline__ void walk_node(
    int gn, int q, unsigned int o, unsigned int e,
    const unsigned int* __restrict__ dest, const unsigned int* __restrict__ seg2,
    const uint2* __restrict__ u0h, const float4* __restrict__ u0,
    const float* __restrict__ W1, const float* __restrict__ b1,
    uint4* __restrict__ h1s) {
    unsigned int cnt = e - o;
    unsigned int hcnt = cnt >> 1;
    unsigned int j0 = o + (q ? hcnt : 0), j1 = q ? e : o + hcnt;
    float4 u = u0[gn];
    float sx = q ? 0.f : u.x, sy = q ? 0.f : u.y, sz = q ? 0.f : u.z;
    unsigned int j = j0;
    for (; j + 4 <= j1; j += 4) {
        unsigned int i0 = sfetch2(dest, seg2, j);
        unsigned int i1 = sfetch2(dest, seg2, j + 1);
        unsigned int i2 = sfetch2(dest, seg2, j + 2);
        unsigned int i3 = sfetch2(dest, seg2, j + 3);
        union { uint2 u; __half2 h[2]; } g0, g1, g2, g3;
        g0.u = u0h[i0]; g1.u = u0h[i1]; g2.u = u0h[i2]; g3.u = u0h[i3];
        float2 a0 = __half22float2(g0.h[0]), c0 = __half22float2(g0.h[1]);
        float2 a1 = __half22float2(g1.h[0]), c1 = __half22float2(g1.h[1]);
        float2 a2 = __half22float2(g2.h[0]), c2 = __half22float2(g2.h[1]);
        float2 a3 = __half22float2(g3.h[0]), c3 = __half22float2(g3.h[1]);
        sx += (a0.x + a1.x) + (a2.x + a3.x);
        sy += (a0.y + a1.y) + (a2.y + a3.y);
        sz += (c0.x + c1.x) + (c2.x + c3.x);
    }
    for (; j < j1; j++) {
        union { uint2 u; __half2 h[2]; } g;
        g.u = u0h[sfetch2(dest, seg2, j)];
        float2 a = __half22float2(g.h[0]);
        sx += a.x; sy += a.y; sz += __half2float(g.h[1].x);
    }
    sx += __shfl_xor(sx, 1, 64);      // pair tid^1 = same node
    sy += __shfl_xor(sy, 1, 64);
    sz += __shfl_xor(sz, 1, 64);
    float di = u.w;
    float a0 = sx * di, a1 = sy * di, a2 = sz * di;
    float hv[16];
#pragma unroll
    for (int i = 0; i < 16; i++) {
        int k = 16 * q + i;
        if (k < 29) {
            float vv = fmaf(a0, W1[k], fmaf(a1, W1[29 + k], fmaf(a2, W1[58 + k], b1[k])));
            hv[i] = fmaxf(vv, 0.0f) * di;   // pre-scaled for next aggregation
        } else {
            hv[i] = (k == 29) ? a0 : (k == 30) ? a1 : a2;   // stash A_hat·inp
        }
    }
    union { __half2 h2[8]; uint4 u4[2]; } pk;
#pragma unroll
    for (int i = 0; i < 8; i++) pk.h2[i] = __floats2half2_rn(hv[2 * i], hv[2 * i + 1]);
    uint4* row = h1s + (size_t)gn * 4 + 2 * q;
    row[0] = pk.u4[0];
    row[1] = pk.u4[1];
}

// build2: single-pass in-LDS node-sort (full bucket staged in dest[68KB], uint4
// reads) -> uint4 flush to ebuf2 -> 2 walk rounds (2 lanes/node x 512 nodes)
// gathering u0h + layer-1 W1/relu epilogue -> fp16 h1s.
// h1s[n][0..28] = relu(W1^T a + b1)*di, [29..31] = a = A_hat·inp (raw).
// LDS: cur 4KB + base2 4KB + dest 68KB = 76KB -> 2 WG/CU.
__global__ __launch_bounds__(1024) void build2_kernel(
    const unsigned int* __restrict__ gcur, const unsigned int* __restrict__ ebuf,
    const unsigned int* __restrict__ rowdeg, const float4* __restrict__ u0,
    const uint2* __restrict__ u0h,
    const float* __restrict__ W1, const float* __restrict__ b1,
    unsigned int* __restrict__ ebuf2, uint4* __restrict__ h1s, int N) {
    __shared__ unsigned int cur[BN2];        // 4KB running cursors (absolute)
    __shared__ unsigned int base2[BN2 + 1];  // 4KB per-node offsets for the walk
    __shared__ unsigned int dest[DEST_CAP];  // 68KB full-bucket staging
    int b = blockIdx.x, tid = threadIdx.x;
    int gn0 = (b << BSH2);
    int n = gn0 + tid;
    unsigned int T = gcur[b]; if (T > CAPB) T = CAPB;
    unsigned int off = (n < N) ? (rowdeg[n] & 0xFFFFu) : T;
    cur[tid] = off; base2[tid] = off;
    if (tid == 0) base2[BN2] = T;
    const unsigned int* seg = ebuf + (size_t)b * CAPB;   // 16B aligned
    unsigned int* seg2 = ebuf2 + (size_t)b * CAPB;       // 16B aligned
    __syncthreads();
    // single-pass scatter (uint4 reads): records node-sorted into dest
    // (overflow -> seg2 direct; essentially never, T <= mean+8sigma)
    unsigned int T4 = T & ~3u;
    for (unsigned int f = 4 * tid; f < T4; f += 4096) {
        v4u p = *(const v4u*)(seg + f);
        {
            unsigned int dl = p.x >> PACK_SHIFT, pos = atomicAdd(&cur[dl], 1u);
            unsigned int sv = p.x & PACK_MASK;
            if (pos < DEST_CAP) dest[pos] = sv; else seg2[pos] = sv;
        }
        {
            unsigned int dl = p.y >> PACK_SHIFT, pos = atomicAdd(&cur[dl], 1u);
            unsigned int sv = p.y & PACK_MASK;
            if (pos < DEST_CAP) dest[pos] = sv; else seg2[pos] = sv;
        }
        {
            unsigned int dl = p.z >> PACK_SHIFT, pos = atomicAdd(&cur[dl], 1u);
            unsigned int sv = p.z & PACK_MASK;
            if (pos < DEST_CAP) dest[pos] = sv; else seg2[pos] = sv;
        }
        {
            unsigned int dl = p.w >> PACK_SHIFT, pos = atomicAdd(&cur[dl], 1u);
            unsigned int sv = p.w & PACK_MASK;
            if (pos < DEST_CAP) dest[pos] = sv; else seg2[pos] = sv;
        }
    }
    for (unsigned int f = T4 + tid; f < T; f += 1024) {
        unsigned int p = seg[f];
        unsigned int dl = p >> PACK_SHIFT, pos = atomicAdd(&cur[dl], 1u);
        unsigned int sv = p & PACK_MASK;
        if (pos < DEST_CAP) dest[pos] = sv; else seg2[pos] = sv;
    }
    __syncthreads();
    // sequential uint4 flush (dest read-only from here; flush range and walk's
    // seg2 fallback range are disjoint)
    unsigned int m = T < DEST_CAP ? T : DEST_CAP;
    unsigned int m4 = m & ~3u;
    for (unsigned int i = 4 * tid; i < m4; i += 4096) {
        v4u w4;
        w4.x = dest[i]; w4.y = dest[i + 1]; w4.z = dest[i + 2]; w4.w = dest[i + 3];
        *(v4u*)(seg2 + i) = w4;
    }
    for (unsigned int i = m4 + tid; i < m; i += 1024) seg2[i] = dest[i];
    // fused layer-1 walk: 2 threads/node, 2 rounds of 512 nodes
    int q = tid & 1;
    int l0 = tid >> 1;
    int gnA = gn0 + l0;
    if (gnA < N)
        walk_node(gnA, q, base2[l0], base2[l0 + 1], dest, seg2, u0h, u0, W1, b1, h1s);
    int l1 = l0 + 512;
    int gnB = gn0 + l1;
    if (gnB < N)
        walk_node(gnB, q, base2[l1], base2[l1 + 1], dest, seg2, u0h, u0, W1, b1, h1s);
}

__device__ __forceinline__ void unpack8(float4 r, float* o) {
    union { float4 f; __half2 h[4]; } u; u.f = r;
    float2 a = __half22float2(u.h[0]); o[0] = a.x; o[1] = a.y;
    float2 b = __half22float2(u.h[1]); o[2] = b.x; o[3] = b.y;
    float2 c = __half22float2(u.h[2]); o[4] = c.x; o[5] = c.y;
    float2 d = __half22float2(u.h[3]); o[6] = d.x; o[7] = d.y;
}

// Fused layer-2 pull + W2/relu/W3: 4 lanes/node, 64B row gather/edge,
// unroll-4 register accumulation, LDS W2, shfl_xor reduce. Writes fp16 zs + out.
// FROZEN at R0 form: request-rate-bound on random 64B gathers (R2: deeper MLP
// null; R1: locality sort null). VGPR 40, occupancy ~61%.
__global__ __launch_bounds__(256) void pull2_kernel(
    const float4* __restrict__ h1f4, const unsigned int* __restrict__ rowdeg,
    const unsigned int* __restrict__ ebuf2, const float4* __restrict__ u0,
    const float* __restrict__ x, const float* __restrict__ y1,
    const float* __restrict__ W2, const float* __restrict__ b2,
    const float* __restrict__ W3, const float* __restrict__ b3,
    __half* __restrict__ zs, float* __restrict__ out, int N) {
    __shared__ float W2l[32 * 29];
    for (int i = threadIdx.x; i < 32 * 29; i += 256) W2l[i] = W2[i];
    int t = blockIdx.x * 256 + threadIdx.x;
    int n = t >> 2, q = t & 3;
    __syncthreads();
    if (n >= N) return;
    unsigned int rd = rowdeg[n];
    const unsigned int* lst = ebuf2 + (size_t)(n >> BSH2) * CAPB + (rd & 0xFFFFu);
    unsigned int cnt = rd >> 16;
    float acc[8] = {0.f, 0.f, 0.f, 0.f, 0.f, 0.f, 0.f, 0.f};
    unsigned int j = 0;
    for (; j + 4 <= cnt; j += 4) {        // 4 outstanding 64B row fetches
        unsigned int s0 = lst[j], s1 = lst[j + 1], s2 = lst[j + 2], s3 = lst[j + 3];
        float4 r0 = h1f4[(size_t)s0 * 4 + q];
        float4 r1 = h1f4[(size_t)s1 * 4 + q];
        float4 r2 = h1f4[(size_t)s2 * 4 + q];
        float4 r3 = h1f4[(size_t)s3 * 4 + q];
        float f0[8], f1[8], f2[8], f3[8];
        unpack8(r0, f0); unpack8(r1, f1); unpack8(r2, f2); unpack8(r3, f3);
#pragma unroll
        for (int i = 0; i < 8; i++) acc[i] += (f0[i] + f1[i]) + (f2[i] + f3[i]);
    }
    for (; j < cnt; j++) {
        float4 r0 = h1f4[(size_t)lst[j] * 4 + q];
        float f0[8]; unpack8(r0, f0);
#pragma unroll
        for (int i = 0; i < 8; i++) acc[i] += f0[i];
    }
    float hs[8];
    { float4 rs = h1f4[(size_t)n * 4 + q]; unpack8(rs, hs); }
    float di = u0[n].w;
    float g[8];
#pragma unroll
    for (int i = 0; i < 8; i++) {
        int jj = 8 * q + i;
        g[i] = (jj < 29) ? (acc[i] + hs[i]) * di   // di*(sum_nbr + self)
                         : hs[i];                  // A_hat·inp (self-stash)
    }
    float p29[29];
#pragma unroll
    for (int kk = 0; kk < 29; kk++) p29[kk] = 0.f;
#pragma unroll
    for (int i = 0; i < 8; i++) {
        float gi = g[i];
        const float* wr = &W2l[(8 * q + i) * 29];
#pragma unroll
        for (int kk = 0; kk < 29; kk++) p29[kk] = fmaf(gi, wr[kk], p29[kk]);
    }
#pragma unroll
    for (int kk = 0; kk < 29; kk++) {
        p29[kk] += __shfl_xor(p29[kk], 1, 64);
        p29[kk] += __shfl_xor(p29[kk], 2, 64);
    }
    if (q == 0) {
        float z = 0.0f;
#pragma unroll
        for (int kk = 0; kk < 29; kk++)
            z = fmaf(fmaxf(p29[kk] + b2[kk], 0.0f), W3[kk], z);
        z = fmaf(x[2 * n], W3[29], z);
        z = fmaf(x[2 * n + 1], W3[30], z);
        z = fmaf(y1[n], W3[31], z);
        zs[n]  = __float2half_rn(z * di);
        out[n] = fmaf(z * di, di, b3[0]);  // self + bias; neighbor sum added by pull3
    }
}

// Layer-3 pull: 4 lanes/node (quartered serial walk, latency-bound pass),
// 2B fp16 gathers from 1MB L2-resident zs, shfl reduce + final scale.
// NT list loads: pull3 is the LAST reader of ebuf2 — no allocate wanted.
__global__ void pull3_kernel(const __half* __restrict__ zs, const float4* __restrict__ u0,
                             const unsigned int* __restrict__ rowdeg,
                             const unsigned int* __restrict__ ebuf2,
                             float* __restrict__ out, int N) {
    int t = blockIdx.x * blockDim.x + threadIdx.x;
    int n = t >> 2, q = t & 3;
    if (n >= N) return;
    unsigned int rd = rowdeg[n];
    const unsigned int* lst = ebuf2 + (size_t)(n >> BSH2) * CAPB + (rd & 0xFFFFu);
    unsigned int cnt = rd >> 16;
    unsigned int qtr = cnt >> 2;
    unsigned int j0 = q * qtr, j1 = (q == 3) ? cnt : j0 + qtr;
    float s = 0.f;
    unsigned int j = j0;
    for (; j + 4 <= j1; j += 4) {
        unsigned int i0 = __builtin_nontemporal_load(lst + j);
        unsigned int i1 = __builtin_nontemporal_load(lst + j + 1);
        unsigned int i2 = __builtin_nontemporal_load(lst + j + 2);
        unsigned int i3 = __builtin_nontemporal_load(lst + j + 3);
        s += (__half2float(zs[i0]) + __half2float(zs[i1]))
           + (__half2float(zs[i2]) + __half2float(zs[i3]));
    }
    for (; j < j1; j++) s += __half2float(zs[__builtin_nontemporal_load(lst + j)]);
    s += __shfl_xor(s, 1, 64);            // 4-lane group = same node
    s += __shfl_xor(s, 2, 64);
    if (q == 0) out[n] += s * u0[n].w;
}

extern "C" void kernel_launch(void* const* d_in, const int* in_sizes, int n_in,
                              void* d_out, int out_size, void* d_ws, size_t ws_size,
                              hipStream_t stream) {
    const float* x  = (const float*)d_in[0];
    const float* y1 = (const float*)d_in[1];
    const int*   ei = (const int*)d_in[2];
    const float* W1 = (const float*)d_in[3];
    const float* b1 = (const float*)d_in[4];
    const float* W2 = (const float*)d_in[5];
    const float* b2 = (const float*)d_in[6];
    const float* W3 = (const float*)d_in[7];
    const float* b3 = (const float*)d_in[8];
    float* out = (float*)d_out;

    int N = in_sizes[1];
    int E = in_sizes[2] / 2;
    const int* src = ei;
    const int* dst = ei + E;

    size_t Ns = (size_t)N;
    int nb = (N + BN2 - 1) >> BSH2;               // 489 buckets (<=512)
    size_t segtot = (size_t)512 * CAPB;           // ~9.2M entries

    float* ws = (float*)d_ws;
    float4*       u0     = (float4*)ws;                              // 4N floats
    __half*       zs     = (__half*)(ws + 4 * Ns);                   // N halves (N floats rsvd)
    unsigned int* rowdeg = (unsigned int*)(ws + 5 * Ns);             // N
    uint2*        u0h    = (uint2*)(ws + 6 * Ns);                    // 2N floats
    unsigned int* gcur   = (unsigned int*)(ws + 8 * Ns);             // 512
    unsigned int* ebuf   = gcur + 512;                               // segtot
    unsigned int* ebuf2  = ebuf + segtot;                            // segtot
    uint4*        h1s    = (uint4*)(ebuf2 + segtot);                 // 16N floats (fp16 rows)

    (void)hipMemsetAsync(gcur, 0, 512 * sizeof(unsigned int), stream);

    const int gS = (E + SPLIT_CH - 1) / SPLIT_CH;
    const int g4 = (4 * N + 255) / 256;
    split_kernel <<<gS, 1024, 0, stream>>>(src, dst, gcur, ebuf, E);
    build1_kernel<<<nb, 1024, 0, stream>>>(gcur, ebuf, x, y1, rowdeg, u0, u0h, N);
    build2_kernel<<<nb, 1024, 0, stream>>>(gcur, ebuf, rowdeg, u0, u0h, W1, b1,
                                           ebuf2, h1s, N);
    pull2_kernel <<<g4, 256, 0, stream>>>((const float4*)h1s, rowdeg, ebuf2, u0,
                                          x, y1, W2, b2, W3, b3, zs, out, N);
    pull3_kernel <<<g4, 256, 0, stream>>>(zs, u0, rowdeg, ebuf2, out, N);
}